// Round 1
// baseline (1293.281 us; speedup 1.0000x reference)
//
#include <hip/hip_runtime.h>
#include <math.h>

#define B  2
#define L  4096
#define D  512
#define H  8
#define DH 64

// ---------------------------------------------------------------------------
// Kernel 1: QKV projection GEMMs. C(8192x512) = X(8192x512) @ W(512x512) + b
// blockIdx.z selects which of Q/K/V. 64x64 tile, BK=16, 256 thr, 4x4 micro.
// ---------------------------------------------------------------------------
#define TS 64
#define KS 16
__global__ __launch_bounds__(256)
void gemm_qkv(const float* __restrict__ Xq, const float* __restrict__ Xk,
              const float* __restrict__ Xv,
              const float* __restrict__ Wq, const float* __restrict__ Wk,
              const float* __restrict__ Wv,
              const float* __restrict__ bq, const float* __restrict__ bk,
              const float* __restrict__ bv,
              float* __restrict__ Qo, float* __restrict__ Ko,
              float* __restrict__ Vo)
{
    const float* X; const float* W; const float* bias; float* C;
    if (blockIdx.z == 0)      { X = Xq; W = Wq; bias = bq; C = Qo; }
    else if (blockIdx.z == 1) { X = Xk; W = Wk; bias = bk; C = Ko; }
    else                      { X = Xv; W = Wv; bias = bv; C = Vo; }

    __shared__ float As[KS][TS + 1];   // [k][m], +1 pad breaks store conflicts
    __shared__ float Bs[KS][TS];       // [k][n]

    const int tid = threadIdx.x;       // 0..255
    const int tx  = tid & 15;          // n micro-col
    const int ty  = tid >> 4;          // m micro-row
    const int m0  = blockIdx.x * TS;   // 8192/64 = 128
    const int n0  = blockIdx.y * TS;   // 512/64  = 8

    float acc[4][4] = {};

    for (int k0 = 0; k0 < D; k0 += KS) {
        // A tile: 64 rows x 16 k. thread t -> row t/4, k-quad (t%4)*4, float4
        {
            const int m  = tid >> 2;
            const int k4 = (tid & 3) << 2;
            const float4 a = *(const float4*)(X + (size_t)(m0 + m) * D + k0 + k4);
            As[k4 + 0][m] = a.x; As[k4 + 1][m] = a.y;
            As[k4 + 2][m] = a.z; As[k4 + 3][m] = a.w;
        }
        // B tile: 16 k x 64 n. thread t -> k t/16, n-quad (t%16)*4, float4
        {
            const int k = tid >> 4;
            const int n = (tid & 15) << 2;
            *(float4*)&Bs[k][n] = *(const float4*)(W + (size_t)(k0 + k) * D + n0 + n);
        }
        __syncthreads();
        #pragma unroll
        for (int kk = 0; kk < KS; kk++) {
            const float a0 = As[kk][ty * 4 + 0];
            const float a1 = As[kk][ty * 4 + 1];
            const float a2 = As[kk][ty * 4 + 2];
            const float a3 = As[kk][ty * 4 + 3];
            const float b0 = Bs[kk][tx * 4 + 0];
            const float b1 = Bs[kk][tx * 4 + 1];
            const float b2 = Bs[kk][tx * 4 + 2];
            const float b3 = Bs[kk][tx * 4 + 3];
            acc[0][0] += a0 * b0; acc[0][1] += a0 * b1; acc[0][2] += a0 * b2; acc[0][3] += a0 * b3;
            acc[1][0] += a1 * b0; acc[1][1] += a1 * b1; acc[1][2] += a1 * b2; acc[1][3] += a1 * b3;
            acc[2][0] += a2 * b0; acc[2][1] += a2 * b1; acc[2][2] += a2 * b2; acc[2][3] += a2 * b3;
            acc[3][0] += a3 * b0; acc[3][1] += a3 * b1; acc[3][2] += a3 * b2; acc[3][3] += a3 * b3;
        }
        __syncthreads();
    }

    #pragma unroll
    for (int i = 0; i < 4; i++) {
        const size_t row = (size_t)(m0 + ty * 4 + i) * D;
        #pragma unroll
        for (int j = 0; j < 4; j++) {
            const int n = n0 + tx * 4 + j;
            C[row + n] = acc[i][j] + bias[n];
        }
    }
}

// ---------------------------------------------------------------------------
// Kernel 2: m[b,h,l] = max_s(q.k_sample_s) - sum_s(q.k_sample_s)/L
// One wave per (b,h,l). lane = dim.
// ---------------------------------------------------------------------------
__global__ __launch_bounds__(256)
void sample_m(const float* __restrict__ Q, const float* __restrict__ K,
              const int* __restrict__ idx, float* __restrict__ m_out, int S)
{
    const int lane = threadIdx.x & 63;
    const int wib  = threadIdx.x >> 6;
    const int wid  = blockIdx.x * 4 + wib;       // 0 .. B*H*L-1
    const int l = wid & (L - 1);
    const int h = (wid >> 12) & (H - 1);
    const int b = wid >> 15;

    const float q = Q[((size_t)b * L + l) * D + h * DH + lane];
    const float* Kb = K + (size_t)b * L * D + h * DH + lane;
    const int* is = idx + (size_t)l * S;

    float vmax = -INFINITY, vsum = 0.f;
    for (int s = 0; s < S; s++) {
        const int j = is[s];
        float prod = q * Kb[(size_t)j * D];
        #pragma unroll
        for (int off = 32; off; off >>= 1) prod += __shfl_xor(prod, off, 64);
        vmax = fmaxf(vmax, prod);
        vsum += prod;
    }
    if (lane == 0) m_out[wid] = vmax - vsum * (1.0f / (float)L);
}

// ---------------------------------------------------------------------------
// Kernel 3: top-NT of m over L per (b,h). 16 blocks. Iterative argmax in LDS.
// ---------------------------------------------------------------------------
__global__ __launch_bounds__(256)
void topk_kernel(const float* __restrict__ m_in, int* __restrict__ m_top, int NT)
{
    __shared__ float vals[L];
    __shared__ float rv[256];
    __shared__ int   ri[256];
    const float* m = m_in + (size_t)blockIdx.x * L;
    for (int i = threadIdx.x; i < L; i += 256) vals[i] = m[i];
    __syncthreads();

    for (int t = 0; t < NT; t++) {
        float best = -INFINITY; int bi = 0x7fffffff;
        for (int i = threadIdx.x; i < L; i += 256) {
            const float v = vals[i];
            if (v > best) { best = v; bi = i; }   // lower index wins ties
        }
        rv[threadIdx.x] = best; ri[threadIdx.x] = bi;
        __syncthreads();
        for (int sArg = 128; sArg > 0; sArg >>= 1) {
            if (threadIdx.x < sArg) {
                const float v2 = rv[threadIdx.x + sArg];
                const int   i2 = ri[threadIdx.x + sArg];
                if (v2 > rv[threadIdx.x] ||
                    (v2 == rv[threadIdx.x] && i2 < ri[threadIdx.x])) {
                    rv[threadIdx.x] = v2; ri[threadIdx.x] = i2;
                }
            }
            __syncthreads();
        }
        if (threadIdx.x == 0) {
            m_top[blockIdx.x * NT + t] = ri[0];
            vals[ri[0]] = -INFINITY;
        }
        __syncthreads();
    }
}

// ---------------------------------------------------------------------------
// Kernels 4+5: cumsum(V) along L per (b,h,d), chunked scan, chunk = 64.
// ---------------------------------------------------------------------------
#define CH 64
__global__ __launch_bounds__(64)
void chunk_sums(const float* __restrict__ V, float* __restrict__ partial)
{
    const int c = blockIdx.x & 63;
    const int h = (blockIdx.x >> 6) & (H - 1);
    const int b = blockIdx.x >> 9;
    const int d = threadIdx.x;
    const float* base = V + (size_t)b * L * D + h * DH + d;
    float s = 0.f;
    const int l0 = c * CH;
    for (int i = 0; i < CH; i++) s += base[(size_t)(l0 + i) * D];
    partial[((size_t)((b * H + h) * 64 + c)) * DH + d] = s;
}

__global__ __launch_bounds__(64)
void cumsum_write(const float* __restrict__ V, const float* __restrict__ partial,
                  float* __restrict__ out)
{
    const int c = blockIdx.x & 63;
    const int h = (blockIdx.x >> 6) & (H - 1);
    const int b = blockIdx.x >> 9;
    const int d = threadIdx.x;
    const float* base  = V   + (size_t)b * L * D + h * DH + d;
    float*       obase = out + (size_t)b * L * D + h * DH + d;
    const float* pb = partial + (size_t)((b * H + h) * 64) * DH + d;
    float acc = 0.f;
    for (int cc = 0; cc < c; cc++) acc += pb[cc * DH];
    const int l0 = c * CH;
    for (int i = 0; i < CH; i++) {
        acc += base[(size_t)(l0 + i) * D];
        obase[(size_t)(l0 + i) * D] = acc;
    }
}

// ---------------------------------------------------------------------------
// Kernel 6: for each selected query u: causal softmax(q.K^T/8) @ V, overwrite
// that output row. Block per (b,h,u), 4 waves, lane = dim.
// ---------------------------------------------------------------------------
__global__ __launch_bounds__(256)
void attn_update(const float* __restrict__ Q, const float* __restrict__ K,
                 const float* __restrict__ V, const int* __restrict__ m_top,
                 float* __restrict__ out, int NT)
{
    __shared__ float s[L];
    __shared__ float red[4];
    __shared__ float red2[4][DH];

    const int u  = blockIdx.x % NT;
    const int bh = blockIdx.x / NT;
    const int h  = bh & (H - 1);
    const int b  = bh >> 3;
    const int lane = threadIdx.x & 63;
    const int w    = threadIdx.x >> 6;

    const int p = m_top[bh * NT + u];
    const int nvalid = p + 1;

    const float* Kb = K + (size_t)b * L * D + h * DH + lane;
    const float* Vb = V + (size_t)b * L * D + h * DH + lane;
    const float  q  = Q[((size_t)b * L + p) * D + h * DH + lane];

    // scores (scaled), only j <= p
    float wmax = -INFINITY;
    for (int j = w; j < nvalid; j += 4) {
        float prod = q * Kb[(size_t)j * D];
        #pragma unroll
        for (int off = 32; off; off >>= 1) prod += __shfl_xor(prod, off, 64);
        prod *= 0.125f;                 // 1/sqrt(64)
        if (lane == 0) s[j] = prod;
        wmax = fmaxf(wmax, prod);
    }
    __syncthreads();                    // s visible
    if (lane == 0) red[w] = wmax;
    __syncthreads();
    const float bmax = fmaxf(fmaxf(red[0], red[1]), fmaxf(red[2], red[3]));

    // exp + sum (store exp back into s)
    float lsum = 0.f;
    for (int j = threadIdx.x; j < nvalid; j += 256) {
        const float e = __expf(s[j] - bmax);
        s[j] = e;
        lsum += e;
    }
    #pragma unroll
    for (int off = 32; off; off >>= 1) lsum += __shfl_xor(lsum, off, 64);
    __syncthreads();                    // s exp-writes + red reads done
    if (lane == 0) red[w] = lsum;
    __syncthreads();
    const float inv = 1.0f / (red[0] + red[1] + red[2] + red[3]);

    // upd[d] = inv * sum_j exp_j * V[j][d]
    float acc = 0.f;
    for (int j = w; j < nvalid; j += 4) {
        acc += s[j] * Vb[(size_t)j * D];
    }
    red2[w][lane] = acc;
    __syncthreads();
    if (w == 0) {
        const float r = red2[0][lane] + red2[1][lane] + red2[2][lane] + red2[3][lane];
        out[((size_t)b * L + p) * D + h * DH + lane] = r * inv;
    }
}

// ---------------------------------------------------------------------------
extern "C" void kernel_launch(void* const* d_in, const int* in_sizes, int n_in,
                              void* d_out, int out_size, void* d_ws, size_t ws_size,
                              hipStream_t stream)
{
    const float* queries = (const float*)d_in[0];
    const float* keys    = (const float*)d_in[1];
    const float* values  = (const float*)d_in[2];
    const float* Wq      = (const float*)d_in[3];
    const float* bq      = (const float*)d_in[4];
    const float* Wk      = (const float*)d_in[5];
    const float* bk      = (const float*)d_in[6];
    const float* Wv      = (const float*)d_in[7];
    const float* bv      = (const float*)d_in[8];
    const int*   idx     = (const int*)d_in[9];
    float* out = (float*)d_out;

    const int S  = in_sizes[9] / L;   // sample_k = 45
    const int NT = S;                 // n_top has the same formula

    const size_t NE = (size_t)B * L * D;   // 4,194,304
    float* Qb      = (float*)d_ws;
    float* Kb      = Qb + NE;
    float* Vb      = Kb + NE;
    float* m_buf   = Vb + NE;              // B*H*L = 65536
    float* partial = m_buf + (size_t)B * H * L;   // B*H*64*64 = 65536
    int*   m_top   = (int*)(partial + (size_t)B * H * 64 * DH);

    gemm_qkv<<<dim3(L * B / TS, D / TS, 3), 256, 0, stream>>>(
        queries, keys, values, Wq, Wk, Wv, bq, bk, bv, Qb, Kb, Vb);

    sample_m<<<B * H * L / 4, 256, 0, stream>>>(Qb, Kb, idx, m_buf, S);

    topk_kernel<<<B * H, 256, 0, stream>>>(m_buf, m_top, NT);

    chunk_sums<<<B * H * 64, 64, 0, stream>>>(Vb, partial);
    cumsum_write<<<B * H * 64, 64, 0, stream>>>(Vb, partial, out);

    attn_update<<<B * H * NT, 256, 0, stream>>>(Qb, Kb, Vb, m_top, out, NT);
}

// Round 2
// 763.866 us; speedup vs baseline: 1.6931x; 1.6931x over previous
//
#include <hip/hip_runtime.h>
#include <math.h>

#define B  2
#define L  4096
#define D  512
#define H  8
#define DH 64

// ---------------------------------------------------------------------------
// Kernel 1: QKV projection GEMMs. C(8192x512) = X(8192x512) @ W(512x512) + b
// blockIdx.z selects which of Q/K/V. 64x64 tile, BK=16, 256 thr, 4x4 micro.
// ---------------------------------------------------------------------------
#define TS 64
#define KS 16
__global__ __launch_bounds__(256)
void gemm_qkv(const float* __restrict__ Xq, const float* __restrict__ Xk,
              const float* __restrict__ Xv,
              const float* __restrict__ Wq, const float* __restrict__ Wk,
              const float* __restrict__ Wv,
              const float* __restrict__ bq, const float* __restrict__ bk,
              const float* __restrict__ bv,
              float* __restrict__ Qo, float* __restrict__ Ko,
              float* __restrict__ Vo)
{
    const float* X; const float* W; const float* bias; float* C;
    if (blockIdx.z == 0)      { X = Xq; W = Wq; bias = bq; C = Qo; }
    else if (blockIdx.z == 1) { X = Xk; W = Wk; bias = bk; C = Ko; }
    else                      { X = Xv; W = Wv; bias = bv; C = Vo; }

    __shared__ float As[KS][TS + 1];
    __shared__ float Bs[KS][TS];

    const int tid = threadIdx.x;
    const int tx  = tid & 15;
    const int ty  = tid >> 4;
    const int m0  = blockIdx.x * TS;
    const int n0  = blockIdx.y * TS;

    float acc[4][4] = {};

    for (int k0 = 0; k0 < D; k0 += KS) {
        {
            const int m  = tid >> 2;
            const int k4 = (tid & 3) << 2;
            const float4 a = *(const float4*)(X + (size_t)(m0 + m) * D + k0 + k4);
            As[k4 + 0][m] = a.x; As[k4 + 1][m] = a.y;
            As[k4 + 2][m] = a.z; As[k4 + 3][m] = a.w;
        }
        {
            const int k = tid >> 4;
            const int n = (tid & 15) << 2;
            *(float4*)&Bs[k][n] = *(const float4*)(W + (size_t)(k0 + k) * D + n0 + n);
        }
        __syncthreads();
        #pragma unroll
        for (int kk = 0; kk < KS; kk++) {
            const float a0 = As[kk][ty * 4 + 0];
            const float a1 = As[kk][ty * 4 + 1];
            const float a2 = As[kk][ty * 4 + 2];
            const float a3 = As[kk][ty * 4 + 3];
            const float b0 = Bs[kk][tx * 4 + 0];
            const float b1 = Bs[kk][tx * 4 + 1];
            const float b2 = Bs[kk][tx * 4 + 2];
            const float b3 = Bs[kk][tx * 4 + 3];
            acc[0][0] += a0 * b0; acc[0][1] += a0 * b1; acc[0][2] += a0 * b2; acc[0][3] += a0 * b3;
            acc[1][0] += a1 * b0; acc[1][1] += a1 * b1; acc[1][2] += a1 * b2; acc[1][3] += a1 * b3;
            acc[2][0] += a2 * b0; acc[2][1] += a2 * b1; acc[2][2] += a2 * b2; acc[2][3] += a2 * b3;
            acc[3][0] += a3 * b0; acc[3][1] += a3 * b1; acc[3][2] += a3 * b2; acc[3][3] += a3 * b3;
        }
        __syncthreads();
    }

    #pragma unroll
    for (int i = 0; i < 4; i++) {
        const size_t row = (size_t)(m0 + ty * 4 + i) * D;
        #pragma unroll
        for (int j = 0; j < 4; j++) {
            const int n = n0 + tx * 4 + j;
            C[row + n] = acc[i][j] + bias[n];
        }
    }
}

// ---------------------------------------------------------------------------
// Kernel 2: m[b,h,l] = max_s(q.k_s) - sum_s(q.k_s)/L
// One wave per query l; LANE = SAMPLE s (45 active lanes). Each lane computes
// a full 64-dim dot via 16 independent float4 loads (no per-sample shuffle
// chain); ONE wave reduction (max+sum) per query at the end.
// ---------------------------------------------------------------------------
__global__ __launch_bounds__(256)
void sample_m(const float* __restrict__ Q, const float* __restrict__ K,
              const int* __restrict__ idx, float* __restrict__ m_out, int S)
{
    __shared__ float qs[4][DH];

    const int lane = threadIdx.x & 63;
    const int wib  = threadIdx.x >> 6;
    const int wid  = blockIdx.x * 4 + wib;       // 0 .. B*H*L-1
    const int l = wid & (L - 1);
    const int h = (wid >> 12) & (H - 1);
    const int b = wid >> 15;

    qs[wib][lane] = Q[((size_t)b * L + l) * D + h * DH + lane];
    __syncthreads();

    float dot = 0.f;
    if (lane < S) {
        const int j = idx[(size_t)l * S + lane];
        const float4* Krow = (const float4*)(K + ((size_t)b * L + j) * D + h * DH);
        const float4* qv   = (const float4*)qs[wib];
        #pragma unroll
        for (int d4 = 0; d4 < DH / 4; d4++) {
            const float4 kv = Krow[d4];
            const float4 qq = qv[d4];
            dot += qq.x * kv.x + qq.y * kv.y + qq.z * kv.z + qq.w * kv.w;
        }
    }
    float pm = (lane < S) ? dot : -INFINITY;
    float ps = (lane < S) ? dot : 0.f;
    #pragma unroll
    for (int off = 32; off; off >>= 1) {
        pm = fmaxf(pm, __shfl_xor(pm, off, 64));
        ps += __shfl_xor(ps, off, 64);
    }
    if (lane == 0) m_out[wid] = pm - ps * (1.0f / (float)L);
}

// ---------------------------------------------------------------------------
// Kernel 3: top-NT of m over L per (b,h). 16 blocks. Iterative argmax in LDS.
// ---------------------------------------------------------------------------
__global__ __launch_bounds__(256)
void topk_kernel(const float* __restrict__ m_in, int* __restrict__ m_top, int NT)
{
    __shared__ float vals[L];
    __shared__ float rv[256];
    __shared__ int   ri[256];
    const float* m = m_in + (size_t)blockIdx.x * L;
    for (int i = threadIdx.x; i < L; i += 256) vals[i] = m[i];
    __syncthreads();

    for (int t = 0; t < NT; t++) {
        float best = -INFINITY; int bi = 0x7fffffff;
        for (int i = threadIdx.x; i < L; i += 256) {
            const float v = vals[i];
            if (v > best) { best = v; bi = i; }
        }
        rv[threadIdx.x] = best; ri[threadIdx.x] = bi;
        __syncthreads();
        for (int sArg = 128; sArg > 0; sArg >>= 1) {
            if (threadIdx.x < sArg) {
                const float v2 = rv[threadIdx.x + sArg];
                const int   i2 = ri[threadIdx.x + sArg];
                if (v2 > rv[threadIdx.x] ||
                    (v2 == rv[threadIdx.x] && i2 < ri[threadIdx.x])) {
                    rv[threadIdx.x] = v2; ri[threadIdx.x] = i2;
                }
            }
            __syncthreads();
        }
        if (threadIdx.x == 0) {
            m_top[blockIdx.x * NT + t] = ri[0];
            vals[ri[0]] = -INFINITY;
        }
        __syncthreads();
    }
}

// ---------------------------------------------------------------------------
// Kernels 4+5: cumsum(V) along L per (b,h,d), chunked scan, chunk = 64.
// ---------------------------------------------------------------------------
#define CH 64
__global__ __launch_bounds__(64)
void chunk_sums(const float* __restrict__ V, float* __restrict__ partial)
{
    const int c = blockIdx.x & 63;
    const int h = (blockIdx.x >> 6) & (H - 1);
    const int b = blockIdx.x >> 9;
    const int d = threadIdx.x;
    const float* base = V + (size_t)b * L * D + h * DH + d;
    float s = 0.f;
    const int l0 = c * CH;
    for (int i = 0; i < CH; i++) s += base[(size_t)(l0 + i) * D];
    partial[((size_t)((b * H + h) * 64 + c)) * DH + d] = s;
}

__global__ __launch_bounds__(64)
void cumsum_write(const float* __restrict__ V, const float* __restrict__ partial,
                  float* __restrict__ out)
{
    const int c = blockIdx.x & 63;
    const int h = (blockIdx.x >> 6) & (H - 1);
    const int b = blockIdx.x >> 9;
    const int d = threadIdx.x;
    const float* base  = V   + (size_t)b * L * D + h * DH + d;
    float*       obase = out + (size_t)b * L * D + h * DH + d;
    const float* pb = partial + (size_t)((b * H + h) * 64) * DH + d;
    float acc = 0.f;
    for (int cc = 0; cc < c; cc++) acc += pb[cc * DH];
    const int l0 = c * CH;
    for (int i = 0; i < CH; i++) {
        acc += base[(size_t)(l0 + i) * D];
        obase[(size_t)(l0 + i) * D] = acc;
    }
}

// ---------------------------------------------------------------------------
// Kernel 6: for each selected query u: causal softmax(q.K^T/8) @ V, overwrite
// that output row. Block per (b,h,u), 256 threads.
//   Pass 1: thread-per-key raw scores -> LDS (no cross-lane ops in loop)
//   Reduce max (tree, once), normalize exp in LDS, reduce sum (tree, once)
//   Pass 2: lane-per-dim weighted V accumulation (coalesced, no cross-lane)
// ---------------------------------------------------------------------------
__global__ __launch_bounds__(256)
void attn_update(const float* __restrict__ Q, const float* __restrict__ K,
                 const float* __restrict__ V, const int* __restrict__ m_top,
                 float* __restrict__ out, int NT)
{
    __shared__ float s[L];
    __shared__ float qsh[DH];
    __shared__ float red[256];
    __shared__ float red2[4][DH];

    const int u  = blockIdx.x % NT;
    const int bh = blockIdx.x / NT;
    const int h  = bh & (H - 1);
    const int b  = bh >> 3;
    const int tid  = threadIdx.x;
    const int lane = tid & 63;
    const int w    = tid >> 6;

    const int p = m_top[bh * NT + u];
    const int nvalid = p + 1;

    const float* Kbase = K + (size_t)b * L * D + h * DH;
    const float* Vbase = V + (size_t)b * L * D + h * DH;

    if (tid < DH) qsh[tid] = Q[((size_t)b * L + p) * D + h * DH + tid];
    __syncthreads();

    // ---- Pass 1: raw scores, thread-per-key ----
    float lmax = -1e30f;
    for (int j = tid; j < nvalid; j += 256) {
        const float4* Krow = (const float4*)(Kbase + (size_t)j * D);
        const float4* qv   = (const float4*)qsh;
        float dot = 0.f;
        #pragma unroll
        for (int d4 = 0; d4 < DH / 4; d4++) {
            const float4 kv = Krow[d4];
            const float4 qq = qv[d4];
            dot += qq.x * kv.x + qq.y * kv.y + qq.z * kv.z + qq.w * kv.w;
        }
        dot *= 0.125f;                  // 1/sqrt(64)
        s[j] = dot;
        lmax = fmaxf(lmax, dot);
    }
    red[tid] = lmax;
    __syncthreads();
    for (int st = 128; st > 0; st >>= 1) {
        if (tid < st) red[tid] = fmaxf(red[tid], red[tid + st]);
        __syncthreads();
    }
    const float M = red[0];
    __syncthreads();                    // red about to be reused

    // ---- normalize: s[j] = exp(s[j]-M), accumulate sum ----
    float lsum = 0.f;
    for (int j = tid; j < nvalid; j += 256) {
        const float e = __expf(s[j] - M);
        s[j] = e;
        lsum += e;
    }
    red[tid] = lsum;
    __syncthreads();
    for (int st = 128; st > 0; st >>= 1) {
        if (tid < st) red[tid] += red[tid + st];
        __syncthreads();
    }
    const float inv = 1.0f / red[0];

    // ---- Pass 2: weighted V, lane-per-dim ----
    float acc = 0.f;
    for (int j = w; j < nvalid; j += 4) {
        acc += s[j] * Vbase[(size_t)j * D + lane];
    }
    red2[w][lane] = acc;
    __syncthreads();
    if (w == 0) {
        const float r = red2[0][lane] + red2[1][lane] + red2[2][lane] + red2[3][lane];
        out[((size_t)b * L + p) * D + h * DH + lane] = r * inv;
    }
}

// ---------------------------------------------------------------------------
extern "C" void kernel_launch(void* const* d_in, const int* in_sizes, int n_in,
                              void* d_out, int out_size, void* d_ws, size_t ws_size,
                              hipStream_t stream)
{
    const float* queries = (const float*)d_in[0];
    const float* keys    = (const float*)d_in[1];
    const float* values  = (const float*)d_in[2];
    const float* Wq      = (const float*)d_in[3];
    const float* bq      = (const float*)d_in[4];
    const float* Wk      = (const float*)d_in[5];
    const float* bk      = (const float*)d_in[6];
    const float* Wv      = (const float*)d_in[7];
    const float* bv      = (const float*)d_in[8];
    const int*   idx     = (const int*)d_in[9];
    float* out = (float*)d_out;

    const int S  = in_sizes[9] / L;   // sample_k = 45
    const int NT = S;                 // n_top has the same formula

    const size_t NE = (size_t)B * L * D;
    float* Qb      = (float*)d_ws;
    float* Kb      = Qb + NE;
    float* Vb      = Kb + NE;
    float* m_buf   = Vb + NE;
    float* partial = m_buf + (size_t)B * H * L;
    int*   m_top   = (int*)(partial + (size_t)B * H * 64 * DH);

    gemm_qkv<<<dim3(L * B / TS, D / TS, 3), 256, 0, stream>>>(
        queries, keys, values, Wq, Wk, Wv, bq, bk, bv, Qb, Kb, Vb);

    sample_m<<<B * H * L / 4, 256, 0, stream>>>(Qb, Kb, idx, m_buf, S);

    topk_kernel<<<B * H, 256, 0, stream>>>(m_buf, m_top, NT);

    chunk_sums<<<B * H * 64, 64, 0, stream>>>(Vb, partial);
    cumsum_write<<<B * H * 64, 64, 0, stream>>>(Vb, partial, out);

    attn_update<<<B * H * NT, 256, 0, stream>>>(Qb, Kb, Vb, m_top, out, NT);
}

// Round 3
// 595.408 us; speedup vs baseline: 2.1721x; 1.2829x over previous
//
#include <hip/hip_runtime.h>
#include <math.h>

#define B  2
#define L  4096
#define D  512
#define H  8
#define DH 64
#define BH (B * H)

// ---------------------------------------------------------------------------
// Kernel 1: QKV projection GEMMs. C(8192x512) = X(8192x512) @ W(512x512) + b
// ---------------------------------------------------------------------------
#define TS 64
#define KS 16
__global__ __launch_bounds__(256)
void gemm_qkv(const float* __restrict__ Xq, const float* __restrict__ Xk,
              const float* __restrict__ Xv,
              const float* __restrict__ Wq, const float* __restrict__ Wk,
              const float* __restrict__ Wv,
              const float* __restrict__ bq, const float* __restrict__ bk,
              const float* __restrict__ bv,
              float* __restrict__ Qo, float* __restrict__ Ko,
              float* __restrict__ Vo)
{
    const float* X; const float* W; const float* bias; float* C;
    if (blockIdx.z == 0)      { X = Xq; W = Wq; bias = bq; C = Qo; }
    else if (blockIdx.z == 1) { X = Xk; W = Wk; bias = bk; C = Ko; }
    else                      { X = Xv; W = Wv; bias = bv; C = Vo; }

    __shared__ float As[KS][TS + 1];
    __shared__ float Bs[KS][TS];

    const int tid = threadIdx.x;
    const int tx  = tid & 15;
    const int ty  = tid >> 4;
    const int m0  = blockIdx.x * TS;
    const int n0  = blockIdx.y * TS;

    float acc[4][4] = {};

    for (int k0 = 0; k0 < D; k0 += KS) {
        {
            const int m  = tid >> 2;
            const int k4 = (tid & 3) << 2;
            const float4 a = *(const float4*)(X + (size_t)(m0 + m) * D + k0 + k4);
            As[k4 + 0][m] = a.x; As[k4 + 1][m] = a.y;
            As[k4 + 2][m] = a.z; As[k4 + 3][m] = a.w;
        }
        {
            const int k = tid >> 4;
            const int n = (tid & 15) << 2;
            *(float4*)&Bs[k][n] = *(const float4*)(W + (size_t)(k0 + k) * D + n0 + n);
        }
        __syncthreads();
        #pragma unroll
        for (int kk = 0; kk < KS; kk++) {
            const float a0 = As[kk][ty * 4 + 0];
            const float a1 = As[kk][ty * 4 + 1];
            const float a2 = As[kk][ty * 4 + 2];
            const float a3 = As[kk][ty * 4 + 3];
            const float b0 = Bs[kk][tx * 4 + 0];
            const float b1 = Bs[kk][tx * 4 + 1];
            const float b2 = Bs[kk][tx * 4 + 2];
            const float b3 = Bs[kk][tx * 4 + 3];
            acc[0][0] += a0 * b0; acc[0][1] += a0 * b1; acc[0][2] += a0 * b2; acc[0][3] += a0 * b3;
            acc[1][0] += a1 * b0; acc[1][1] += a1 * b1; acc[1][2] += a1 * b2; acc[1][3] += a1 * b3;
            acc[2][0] += a2 * b0; acc[2][1] += a2 * b1; acc[2][2] += a2 * b2; acc[2][3] += a2 * b3;
            acc[3][0] += a3 * b0; acc[3][1] += a3 * b1; acc[3][2] += a3 * b2; acc[3][3] += a3 * b3;
        }
        __syncthreads();
    }

    #pragma unroll
    for (int i = 0; i < 4; i++) {
        const size_t row = (size_t)(m0 + ty * 4 + i) * D;
        #pragma unroll
        for (int j = 0; j < 4; j++) {
            const int n = n0 + tx * 4 + j;
            C[row + n] = acc[i][j] + bias[n];
        }
    }
}

// ---------------------------------------------------------------------------
// Kernel 2: m[b,h,l] = max_s(q.k_s) - sum_s(q.k_s)/L. Wave per query,
// lane = sample. One wave reduction per query.
// ---------------------------------------------------------------------------
__global__ __launch_bounds__(256)
void sample_m(const float* __restrict__ Q, const float* __restrict__ K,
              const int* __restrict__ idx, float* __restrict__ m_out, int S)
{
    __shared__ float qs[4][DH];

    const int lane = threadIdx.x & 63;
    const int wib  = threadIdx.x >> 6;
    const int wid  = blockIdx.x * 4 + wib;
    const int l = wid & (L - 1);
    const int h = (wid >> 12) & (H - 1);
    const int b = wid >> 15;

    qs[wib][lane] = Q[((size_t)b * L + l) * D + h * DH + lane];
    __syncthreads();

    float dot = 0.f;
    if (lane < S) {
        const int j = idx[(size_t)l * S + lane];
        const float4* Krow = (const float4*)(K + ((size_t)b * L + j) * D + h * DH);
        const float4* qv   = (const float4*)qs[wib];
        #pragma unroll
        for (int d4 = 0; d4 < DH / 4; d4++) {
            const float4 kv = Krow[d4];
            const float4 qq = qv[d4];
            dot += qq.x * kv.x + qq.y * kv.y + qq.z * kv.z + qq.w * kv.w;
        }
    }
    float pm = (lane < S) ? dot : -INFINITY;
    float ps = (lane < S) ? dot : 0.f;
    #pragma unroll
    for (int off = 32; off; off >>= 1) {
        pm = fmaxf(pm, __shfl_xor(pm, off, 64));
        ps += __shfl_xor(ps, off, 64);
    }
    if (lane == 0) m_out[wid] = pm - ps * (1.0f / (float)L);
}

// ---------------------------------------------------------------------------
// Kernel 3: top-NT of m over L per (b,h). Iterative argmax in LDS.
// ---------------------------------------------------------------------------
__global__ __launch_bounds__(256)
void topk_kernel(const float* __restrict__ m_in, int* __restrict__ m_top, int NT)
{
    __shared__ float vals[L];
    __shared__ float rv[256];
    __shared__ int   ri[256];
    const float* m = m_in + (size_t)blockIdx.x * L;
    for (int i = threadIdx.x; i < L; i += 256) vals[i] = m[i];
    __syncthreads();

    for (int t = 0; t < NT; t++) {
        float best = -INFINITY; int bi = 0x7fffffff;
        for (int i = threadIdx.x; i < L; i += 256) {
            const float v = vals[i];
            if (v > best) { best = v; bi = i; }
        }
        rv[threadIdx.x] = best; ri[threadIdx.x] = bi;
        __syncthreads();
        for (int sArg = 128; sArg > 0; sArg >>= 1) {
            if (threadIdx.x < sArg) {
                const float v2 = rv[threadIdx.x + sArg];
                const int   i2 = ri[threadIdx.x + sArg];
                if (v2 > rv[threadIdx.x] ||
                    (v2 == rv[threadIdx.x] && i2 < ri[threadIdx.x])) {
                    rv[threadIdx.x] = v2; ri[threadIdx.x] = i2;
                }
            }
            __syncthreads();
        }
        if (threadIdx.x == 0) {
            m_top[blockIdx.x * NT + t] = ri[0];
            vals[ri[0]] = -INFINITY;
        }
        __syncthreads();
    }
}

// ---------------------------------------------------------------------------
// Kernels 4+5: cumsum(V) along L per (b,h,d), chunked scan, chunk = 64.
// ---------------------------------------------------------------------------
#define CH 64
__global__ __launch_bounds__(64)
void chunk_sums(const float* __restrict__ V, float* __restrict__ partial)
{
    const int c = blockIdx.x & 63;
    const int h = (blockIdx.x >> 6) & (H - 1);
    const int b = blockIdx.x >> 9;
    const int d = threadIdx.x;
    const float* base = V + (size_t)b * L * D + h * DH + d;
    float s = 0.f;
    const int l0 = c * CH;
    for (int i = 0; i < CH; i++) s += base[(size_t)(l0 + i) * D];
    partial[((size_t)((b * H + h) * 64 + c)) * DH + d] = s;
}

__global__ __launch_bounds__(64)
void cumsum_write(const float* __restrict__ V, const float* __restrict__ partial,
                  float* __restrict__ out)
{
    const int c = blockIdx.x & 63;
    const int h = (blockIdx.x >> 6) & (H - 1);
    const int b = blockIdx.x >> 9;
    const int d = threadIdx.x;
    const float* base  = V   + (size_t)b * L * D + h * DH + d;
    float*       obase = out + (size_t)b * L * D + h * DH + d;
    const float* pb = partial + (size_t)((b * H + h) * 64) * DH + d;
    float acc = 0.f;
    for (int cc = 0; cc < c; cc++) acc += pb[cc * DH];
    const int l0 = c * CH;
    for (int i = 0; i < CH; i++) {
        acc += base[(size_t)(l0 + i) * D];
        obase[(size_t)(l0 + i) * D] = acc;
    }
}

// ---------------------------------------------------------------------------
// Kernel 6a: raw scores for all (u, j). Grid (keyChunk=8, uGroup=3, bh=16).
// 512 keys/chunk (2 per thread, K rows in regs), 15 u/group (q in LDS,
// broadcast reads). Stores 0 beyond the causal bound p -> scores buffer is
// fully initialized every launch.
// ---------------------------------------------------------------------------
__global__ __launch_bounds__(256)
void attn_scores(const float* __restrict__ Q, const float* __restrict__ K,
                 const int* __restrict__ m_top, float* __restrict__ scores,
                 int NT)
{
    __shared__ float qsh[15][DH];
    __shared__ int   psh[15];

    const int bh = blockIdx.z;
    const int h  = bh & (H - 1);
    const int b  = bh >> 3;
    const int ug = blockIdx.y;              // u base = ug*15
    const int j0 = blockIdx.x * 512;
    const int tid = threadIdx.x;

    for (int i = tid; i < 15 * DH; i += 256) {
        const int u = i >> 6, d = i & 63;
        const int p = m_top[bh * NT + ug * 15 + u];
        if (d == 0) psh[u] = p;
        qsh[u][d] = Q[((size_t)b * L + p) * D + h * DH + d];
    }
    __syncthreads();

    const float* Kb = K + (size_t)b * L * D + h * DH;
    const int ja = j0 + tid;
    const int jb = ja + 256;
    float4 k0[16], k1[16];
    {
        const float4* ra = (const float4*)(Kb + (size_t)ja * D);
        const float4* rb = (const float4*)(Kb + (size_t)jb * D);
        #pragma unroll
        for (int i = 0; i < 16; i++) { k0[i] = ra[i]; k1[i] = rb[i]; }
    }

    for (int u = 0; u < 15; u++) {
        const int p = psh[u];
        const float4* qv = (const float4*)qsh[u];
        float d0 = 0.f, d1 = 0.f;
        #pragma unroll
        for (int i = 0; i < 16; i++) {
            const float4 q4 = qv[i];
            d0 += q4.x * k0[i].x + q4.y * k0[i].y + q4.z * k0[i].z + q4.w * k0[i].w;
            d1 += q4.x * k1[i].x + q4.y * k1[i].y + q4.z * k1[i].z + q4.w * k1[i].w;
        }
        float* srow = scores + (size_t)(bh * NT + ug * 15 + u) * L;
        srow[ja] = (ja <= p) ? d0 * 0.125f : 0.f;
        srow[jb] = (jb <= p) ? d1 * 0.125f : 0.f;
    }
}

// ---------------------------------------------------------------------------
// Kernel 6b: per (bh,u): max over [0..p], exp in place, store sum.
// ---------------------------------------------------------------------------
__global__ __launch_bounds__(256)
void attn_softmax(float* __restrict__ scores, const int* __restrict__ m_top,
                  float* __restrict__ sums)
{
    __shared__ float red[256];
    const int gu = blockIdx.x;
    const int p  = m_top[gu];
    const int n  = p + 1;
    float* s = scores + (size_t)gu * L;
    const int tid = threadIdx.x;

    float lmax = -1e30f;
    for (int j = tid; j < n; j += 256) lmax = fmaxf(lmax, s[j]);
    red[tid] = lmax;
    __syncthreads();
    for (int st = 128; st > 0; st >>= 1) {
        if (tid < st) red[tid] = fmaxf(red[tid], red[tid + st]);
        __syncthreads();
    }
    const float M = red[0];
    __syncthreads();

    float lsum = 0.f;
    for (int j = tid; j < n; j += 256) {
        const float e = __expf(s[j] - M);
        s[j] = e;
        lsum += e;
    }
    red[tid] = lsum;
    __syncthreads();
    for (int st = 128; st > 0; st >>= 1) {
        if (tid < st) red[tid] += red[tid + st];
        __syncthreads();
    }
    if (tid == 0) sums[gu] = red[0];
}

// ---------------------------------------------------------------------------
// Kernel 6c: weighted-V partials. Grid (keyChunk=16, bh=16). 256 keys/chunk,
// thread = (jg = tid>>6 covering 64 keys, d = tid&63). V cached in 64 regs
// (coalesced loads); weights broadcast from LDS. Writes
// partial[(gu*64 + chunk*4 + jg)*64 + d] — always stored (scratch poisoned).
// ---------------------------------------------------------------------------
__global__ __launch_bounds__(256)
void attn_wv(const float* __restrict__ scores, const float* __restrict__ V,
             const int* __restrict__ m_top, float* __restrict__ partial,
             int NT)
{
    __shared__ float ssh[45][256];   // 46 KB
    __shared__ int   psh[45];

    const int bh = blockIdx.y;
    const int h  = bh & (H - 1);
    const int b  = bh >> 3;
    const int j0 = blockIdx.x * 256;
    const int tid = threadIdx.x;
    const int d   = tid & 63;
    const int jg  = tid >> 6;

    if (tid < NT) psh[tid] = m_top[bh * NT + tid];

    // stage V: 64 keys per thread-group, lane = d (coalesced)
    const float* Vb = V + (size_t)b * L * D + h * DH + d;
    const int jbase = j0 + jg * 64;
    float vreg[64];
    #pragma unroll
    for (int i = 0; i < 64; i++) vreg[i] = Vb[(size_t)(jbase + i) * D];

    // stage weights for all u, this chunk (zeros beyond p already in buffer)
    for (int i = tid; i < NT * 256; i += 256) {
        const int u = i >> 8, j = i & 255;
        ssh[u][j] = scores[(size_t)(bh * NT + u) * L + j0 + j];
    }
    __syncthreads();

    for (int u = 0; u < NT; u++) {
        float acc = 0.f;
        if (psh[u] >= jbase) {
            const float* w = &ssh[u][jg * 64];
            #pragma unroll 8
            for (int i = 0; i < 64; i++) acc += w[i] * vreg[i];
        }
        partial[((size_t)(bh * NT + u) * 64 + blockIdx.x * 4 + jg) * 64 + d] = acc;
    }
}

// ---------------------------------------------------------------------------
// Kernel 6d: reduce 64 partials per (gu,d), divide by softmax sum, overwrite
// the cumsum output row.
// ---------------------------------------------------------------------------
__global__ __launch_bounds__(64)
void attn_final(const float* __restrict__ partial, const float* __restrict__ sums,
                const int* __restrict__ m_top, float* __restrict__ out, int NT)
{
    const int gu = blockIdx.x;
    const int bh = gu / NT;
    const int h  = bh & (H - 1);
    const int b  = bh >> 3;
    const int p  = m_top[gu];
    const int d  = threadIdx.x;

    const float* pp = partial + (size_t)gu * 64 * 64 + d;
    float acc = 0.f;
    #pragma unroll 8
    for (int c = 0; c < 64; c++) acc += pp[c * 64];
    out[((size_t)b * L + p) * D + h * DH + d] = acc / sums[gu];
}

// ---------------------------------------------------------------------------
extern "C" void kernel_launch(void* const* d_in, const int* in_sizes, int n_in,
                              void* d_out, int out_size, void* d_ws, size_t ws_size,
                              hipStream_t stream)
{
    const float* queries = (const float*)d_in[0];
    const float* keys    = (const float*)d_in[1];
    const float* values  = (const float*)d_in[2];
    const float* Wq      = (const float*)d_in[3];
    const float* bq      = (const float*)d_in[4];
    const float* Wk      = (const float*)d_in[5];
    const float* bk      = (const float*)d_in[6];
    const float* Wv      = (const float*)d_in[7];
    const float* bv      = (const float*)d_in[8];
    const int*   idx     = (const int*)d_in[9];
    float* out = (float*)d_out;

    const int S  = in_sizes[9] / L;   // sample_k = 45
    const int NT = S;                 // n_top has the same formula

    const size_t NE = (size_t)B * L * D;
    float* Qb      = (float*)d_ws;
    float* Kb      = Qb + NE;
    float* Vb      = Kb + NE;
    float* m_buf   = Vb + NE;                           // B*H*L
    float* cs_part = m_buf + (size_t)BH * L;            // BH*64*DH
    int*   m_top   = (int*)(cs_part + (size_t)BH * 64 * DH);
    float* scores  = (float*)(m_top + 1024);            // BH*NT*L
    float* sums    = scores + (size_t)BH * NT * L;      // BH*NT
    float* wv_part = sums + 1024;                       // BH*NT*64*DH

    gemm_qkv<<<dim3(L * B / TS, D / TS, 3), 256, 0, stream>>>(
        queries, keys, values, Wq, Wk, Wv, bq, bk, bv, Qb, Kb, Vb);

    sample_m<<<BH * L / 4, 256, 0, stream>>>(Qb, Kb, idx, m_buf, S);

    topk_kernel<<<BH, 256, 0, stream>>>(m_buf, m_top, NT);

    chunk_sums<<<BH * 64, 64, 0, stream>>>(Vb, cs_part);
    cumsum_write<<<BH * 64, 64, 0, stream>>>(Vb, cs_part, out);

    attn_scores<<<dim3(8, 3, BH), 256, 0, stream>>>(Qb, Kb, m_top, scores, NT);
    attn_softmax<<<BH * NT, 256, 0, stream>>>(scores, m_top, sums);
    attn_wv<<<dim3(16, BH), 256, 0, stream>>>(scores, Vb, m_top, wv_part, NT);
    attn_final<<<BH * NT, 64, 0, stream>>>(wv_part, sums, m_top, out, NT);
}

// Round 4
// 491.321 us; speedup vs baseline: 2.6323x; 1.2119x over previous
//
#include <hip/hip_runtime.h>
#include <math.h>

#define B  2
#define L  4096
#define D  512
#define H  8
#define DH 64
#define BH (B * H)
#define K3 1536          // tripled-K for the bf16 split GEMM
#define XPW 1024         // Xp width: [hi | lo]

typedef short s16x8 __attribute__((ext_vector_type(8)));
typedef float f32x4 __attribute__((ext_vector_type(4)));

#define AS1 __attribute__((address_space(1)))
#define AS3 __attribute__((address_space(3)))

__device__ __forceinline__ void lds_load16(const void* g, void* l) {
    __builtin_amdgcn_global_load_lds((const AS1 unsigned int*)g,
                                     (AS3 unsigned int*)l, 16, 0, 0);
}

__device__ __forceinline__ unsigned short f2bf(float x) {
    union { float f; unsigned u; } v; v.f = x;
    unsigned u = v.u;
    return (unsigned short)((u + 0x7fff + ((u >> 16) & 1)) >> 16);
}
__device__ __forceinline__ float bf2f(unsigned short h) {
    union { float f; unsigned u; } v; v.u = ((unsigned)h) << 16;
    return v.f;
}

// ---------------------------------------------------------------------------
// Prep 1: split X (fp32 8192x512) -> Xp (bf16 8192x1024): [hi | lo]
// ---------------------------------------------------------------------------
__global__ __launch_bounds__(256)
void split_x(const float* __restrict__ q, const float* __restrict__ k,
             const float* __restrict__ v, unsigned short* __restrict__ Xp)
{
    const size_t g = (size_t)blockIdx.x * 256 + threadIdx.x;  // 0..3*8192*128
    const size_t per = (size_t)8192 * 128;
    const int e = (int)(g / per);
    const size_t rem = g - (size_t)e * per;
    const int m  = (int)(rem >> 7);
    const int kq = (int)(rem & 127) << 2;

    const float* X = (e == 0) ? q : (e == 1) ? k : v;
    const float4 x = *(const float4*)(X + (size_t)m * 512 + kq);

    unsigned short h0 = f2bf(x.x), h1 = f2bf(x.y), h2 = f2bf(x.z), h3 = f2bf(x.w);
    unsigned short l0 = f2bf(x.x - bf2f(h0)), l1 = f2bf(x.y - bf2f(h1));
    unsigned short l2 = f2bf(x.z - bf2f(h2)), l3 = f2bf(x.w - bf2f(h3));

    unsigned short* dst = Xp + (size_t)e * 8192 * XPW + (size_t)m * XPW + kq;
    *(ushort4*)(dst)       = make_ushort4(h0, h1, h2, h3);
    *(ushort4*)(dst + 512) = make_ushort4(l0, l1, l2, l3);
}

// ---------------------------------------------------------------------------
// Prep 2: W (fp32 512x512, [k][n]) -> WpT (bf16 512x1536, [n][k']):
//   k' in [0,512): hi   [512,1024): lo   [1024,1536): hi
// Transpose via LDS tile.
// ---------------------------------------------------------------------------
__global__ __launch_bounds__(256)
void split_w(const float* __restrict__ wq, const float* __restrict__ wk,
             const float* __restrict__ wv, unsigned short* __restrict__ WpT)
{
    __shared__ float t[64][65];
    const int e  = blockIdx.z;
    const int k0 = blockIdx.x * 64;
    const int n0 = blockIdx.y * 64;
    const float* W = (e == 0) ? wq : (e == 1) ? wk : wv;
    const int tid = threadIdx.x;

    for (int idx = tid; idx < 64 * 16; idx += 256) {
        const int i = idx >> 4, j4 = (idx & 15) << 2;
        *(float4*)&t[i][j4] = *(const float4*)(W + (size_t)(k0 + i) * 512 + n0 + j4);
    }
    __syncthreads();

    const int n_loc = tid >> 2;
    const int kq    = (tid & 3) << 4;
    unsigned short h[16], l[16];
    #pragma unroll
    for (int tt = 0; tt < 16; tt++) {
        const float x = t[kq + tt][n_loc];
        h[tt] = f2bf(x);
        l[tt] = f2bf(x - bf2f(h[tt]));
    }
    unsigned short* base = WpT + (size_t)e * 512 * K3 + (size_t)(n0 + n_loc) * K3 + k0 + kq;
    #pragma unroll
    for (int g4 = 0; g4 < 4; g4++) {
        ushort4 hv = make_ushort4(h[g4*4], h[g4*4+1], h[g4*4+2], h[g4*4+3]);
        ushort4 lv = make_ushort4(l[g4*4], l[g4*4+1], l[g4*4+2], l[g4*4+3]);
        *(ushort4*)(base + g4*4)        = hv;   // seg0: hi
        *(ushort4*)(base + 512 + g4*4)  = lv;   // seg1: lo
        *(ushort4*)(base + 1024 + g4*4) = hv;   // seg2: hi
    }
}

// ---------------------------------------------------------------------------
// Kernel 1: bf16-split MFMA GEMM. C[m][n] = sum_k' Xp[m][kA(k')] * WpT[n][k']
// 128x128 tile, BK=32, 4 waves (2x2), 16x mfma_f32_16x16x32_bf16 per wave per
// K-step. global_load_lds width-16 staging with XOR-swizzled LDS layout
// (octet ^ (row>>1)&3) -> conflict-free ds_read_b128.
// ---------------------------------------------------------------------------
__global__ __launch_bounds__(256)
void gemm_mfma(const unsigned short* __restrict__ Xp,
               const unsigned short* __restrict__ WpT,
               const float* __restrict__ bq, const float* __restrict__ bk,
               const float* __restrict__ bv,
               float* __restrict__ Qo, float* __restrict__ Ko,
               float* __restrict__ Vo)
{
    __shared__ __align__(16) unsigned short smA[4096];  // 128 rows x 32 k
    __shared__ __align__(16) unsigned short smB[4096];  // 128 n    x 32 k

    const int e = blockIdx.z;
    const float* bias = (e == 0) ? bq : (e == 1) ? bk : bv;
    float* C          = (e == 0) ? Qo : (e == 1) ? Ko : Vo;
    const unsigned short* Ag = Xp  + (size_t)e * 8192 * XPW;
    const unsigned short* Bg = WpT + (size_t)e * 512 * K3;

    const int tid  = threadIdx.x;
    const int lane = tid & 63;
    const int wid  = tid >> 6;
    const int wm   = wid & 1;
    const int wn   = wid >> 1;
    const int m0   = blockIdx.x * 128;
    const int n0g  = blockIdx.y * 128;

    // staging addresses
    const int r1 = tid >> 2;                                  // row 0..63
    const int c8 = (((tid & 3) ^ ((r1 >> 1) & 3)) << 3);      // swizzled octet (ushorts)
    const unsigned short* agp = Ag + (size_t)(m0 + r1) * XPW + c8;
    const unsigned short* bgp = Bg + (size_t)(n0g + r1) * K3 + c8;
    unsigned short* lA1 = smA + (size_t)(tid & ~63) * 8;      // wave-uniform base
    unsigned short* lA2 = lA1 + 2048;
    unsigned short* lB1 = smB + (size_t)(tid & ~63) * 8;
    unsigned short* lB2 = lB1 + 2048;

    // fragment read addresses
    const int r    = lane & 15;
    const int quad = lane >> 4;
    const int swz  = ((quad ^ ((lane >> 1) & 3)) << 4);       // bytes
    const char* pA = (const char*)smA + (wm * 64 + r) * 64 + swz;
    const char* pB = (const char*)smB + (wn * 64 + r) * 64 + swz;

    f32x4 acc[4][4];
    #pragma unroll
    for (int i = 0; i < 4; i++)
        #pragma unroll
        for (int j = 0; j < 4; j++)
            acc[i][j] = (f32x4){0.f, 0.f, 0.f, 0.f};

    for (int k0 = 0; k0 < K3; k0 += 32) {
        const int kA = (k0 < 512) ? k0 : k0 - 512;   // hi, hi, lo
        lds_load16(agp + kA, lA1);
        lds_load16(agp + (size_t)64 * XPW + kA, lA2);
        lds_load16(bgp + k0, lB1);
        lds_load16(bgp + (size_t)64 * K3 + k0, lB2);
        __syncthreads();

        s16x8 af[4], bf[4];
        #pragma unroll
        for (int mt = 0; mt < 4; mt++) af[mt] = *(const s16x8*)(pA + mt * 1024);
        #pragma unroll
        for (int nt = 0; nt < 4; nt++) bf[nt] = *(const s16x8*)(pB + nt * 1024);
        #pragma unroll
        for (int mt = 0; mt < 4; mt++)
            #pragma unroll
            for (int nt = 0; nt < 4; nt++)
                acc[mt][nt] = __builtin_amdgcn_mfma_f32_16x16x32_bf16(
                    af[mt], bf[nt], acc[mt][nt], 0, 0, 0);
        __syncthreads();
    }

    // epilogue: D[m = quad*4+i][n = lane&15] per 16x16 tile
    #pragma unroll
    for (int nt = 0; nt < 4; nt++) {
        const int col = n0g + wn * 64 + nt * 16 + r;
        const float bb = bias[col];
        #pragma unroll
        for (int mt = 0; mt < 4; mt++) {
            const int row0 = m0 + wm * 64 + mt * 16 + quad * 4;
            #pragma unroll
            for (int i = 0; i < 4; i++)
                C[(size_t)(row0 + i) * 512 + col] = acc[mt][nt][i] + bb;
        }
    }
}

// ---------------------------------------------------------------------------
// Kernel 2: m[b,h,l] = max_s(q.k_s) - sum_s(q.k_s)/L. Wave per query,
// lane = sample. One wave reduction per query.
// ---------------------------------------------------------------------------
__global__ __launch_bounds__(256)
void sample_m(const float* __restrict__ Q, const float* __restrict__ K,
              const int* __restrict__ idx, float* __restrict__ m_out, int S)
{
    __shared__ float qs[4][DH];

    const int lane = threadIdx.x & 63;
    const int wib  = threadIdx.x >> 6;
    const int wid  = blockIdx.x * 4 + wib;
    const int l = wid & (L - 1);
    const int h = (wid >> 12) & (H - 1);
    const int b = wid >> 15;

    qs[wib][lane] = Q[((size_t)b * L + l) * D + h * DH + lane];
    __syncthreads();

    float dot = 0.f;
    if (lane < S) {
        const int j = idx[(size_t)l * S + lane];
        const float4* Krow = (const float4*)(K + ((size_t)b * L + j) * D + h * DH);
        const float4* qv   = (const float4*)qs[wib];
        #pragma unroll
        for (int d4 = 0; d4 < DH / 4; d4++) {
            const float4 kv = Krow[d4];
            const float4 qq = qv[d4];
            dot += qq.x * kv.x + qq.y * kv.y + qq.z * kv.z + qq.w * kv.w;
        }
    }
    float pm = (lane < S) ? dot : -INFINITY;
    float ps = (lane < S) ? dot : 0.f;
    #pragma unroll
    for (int off = 32; off; off >>= 1) {
        pm = fmaxf(pm, __shfl_xor(pm, off, 64));
        ps += __shfl_xor(ps, off, 64);
    }
    if (lane == 0) m_out[wid] = pm - ps * (1.0f / (float)L);
}

// ---------------------------------------------------------------------------
// Kernel 3: top-NT of m over L per (b,h). Iterative argmax in LDS.
// ---------------------------------------------------------------------------
__global__ __launch_bounds__(256)
void topk_kernel(const float* __restrict__ m_in, int* __restrict__ m_top, int NT)
{
    __shared__ float vals[L];
    __shared__ float rv[256];
    __shared__ int   ri[256];
    const float* m = m_in + (size_t)blockIdx.x * L;
    for (int i = threadIdx.x; i < L; i += 256) vals[i] = m[i];
    __syncthreads();

    for (int t = 0; t < NT; t++) {
        float best = -INFINITY; int bi = 0x7fffffff;
        for (int i = threadIdx.x; i < L; i += 256) {
            const float v = vals[i];
            if (v > best) { best = v; bi = i; }
        }
        rv[threadIdx.x] = best; ri[threadIdx.x] = bi;
        __syncthreads();
        for (int sArg = 128; sArg > 0; sArg >>= 1) {
            if (threadIdx.x < sArg) {
                const float v2 = rv[threadIdx.x + sArg];
                const int   i2 = ri[threadIdx.x + sArg];
                if (v2 > rv[threadIdx.x] ||
                    (v2 == rv[threadIdx.x] && i2 < ri[threadIdx.x])) {
                    rv[threadIdx.x] = v2; ri[threadIdx.x] = i2;
                }
            }
            __syncthreads();
        }
        if (threadIdx.x == 0) {
            m_top[blockIdx.x * NT + t] = ri[0];
            vals[ri[0]] = -INFINITY;
        }
        __syncthreads();
    }
}

// ---------------------------------------------------------------------------
// Kernels 4+5: cumsum(V) along L per (b,h,d), chunked scan, chunk = 64.
// ---------------------------------------------------------------------------
#define CH 64
__global__ __launch_bounds__(64)
void chunk_sums(const float* __restrict__ V, float* __restrict__ partial)
{
    const int c = blockIdx.x & 63;
    const int h = (blockIdx.x >> 6) & (H - 1);
    const int b = blockIdx.x >> 9;
    const int d = threadIdx.x;
    const float* base = V + (size_t)b * L * D + h * DH + d;
    float s = 0.f;
    const int l0 = c * CH;
    for (int i = 0; i < CH; i++) s += base[(size_t)(l0 + i) * D];
    partial[((size_t)((b * H + h) * 64 + c)) * DH + d] = s;
}

__global__ __launch_bounds__(64)
void cumsum_write(const float* __restrict__ V, const float* __restrict__ partial,
                  float* __restrict__ out)
{
    const int c = blockIdx.x & 63;
    const int h = (blockIdx.x >> 6) & (H - 1);
    const int b = blockIdx.x >> 9;
    const int d = threadIdx.x;
    const float* base  = V   + (size_t)b * L * D + h * DH + d;
    float*       obase = out + (size_t)b * L * D + h * DH + d;
    const float* pb = partial + (size_t)((b * H + h) * 64) * DH + d;
    float acc = 0.f;
    for (int cc = 0; cc < c; cc++) acc += pb[cc * DH];
    const int l0 = c * CH;
    for (int i = 0; i < CH; i++) {
        acc += base[(size_t)(l0 + i) * D];
        obase[(size_t)(l0 + i) * D] = acc;
    }
}

// ---------------------------------------------------------------------------
// Kernel 6a: raw scores for all (u, j). Grid (keyChunk=8, uGroup=3, bh=16).
// ---------------------------------------------------------------------------
__global__ __launch_bounds__(256)
void attn_scores(const float* __restrict__ Q, const float* __restrict__ K,
                 const int* __restrict__ m_top, float* __restrict__ scores,
                 int NT)
{
    __shared__ float qsh[15][DH];
    __shared__ int   psh[15];

    const int bh = blockIdx.z;
    const int h  = bh & (H - 1);
    const int b  = bh >> 3;
    const int ug = blockIdx.y;
    const int j0 = blockIdx.x * 512;
    const int tid = threadIdx.x;

    for (int i = tid; i < 15 * DH; i += 256) {
        const int u = i >> 6, d = i & 63;
        const int p = m_top[bh * NT + ug * 15 + u];
        if (d == 0) psh[u] = p;
        qsh[u][d] = Q[((size_t)b * L + p) * D + h * DH + d];
    }
    __syncthreads();

    const float* Kb = K + (size_t)b * L * D + h * DH;
    const int ja = j0 + tid;
    const int jb = ja + 256;
    float4 k0[16], k1[16];
    {
        const float4* ra = (const float4*)(Kb + (size_t)ja * D);
        const float4* rb = (const float4*)(Kb + (size_t)jb * D);
        #pragma unroll
        for (int i = 0; i < 16; i++) { k0[i] = ra[i]; k1[i] = rb[i]; }
    }

    for (int u = 0; u < 15; u++) {
        const int p = psh[u];
        const float4* qv = (const float4*)qsh[u];
        float d0 = 0.f, d1 = 0.f;
        #pragma unroll
        for (int i = 0; i < 16; i++) {
            const float4 q4 = qv[i];
            d0 += q4.x * k0[i].x + q4.y * k0[i].y + q4.z * k0[i].z + q4.w * k0[i].w;
            d1 += q4.x * k1[i].x + q4.y * k1[i].y + q4.z * k1[i].z + q4.w * k1[i].w;
        }
        float* srow = scores + (size_t)(bh * NT + ug * 15 + u) * L;
        srow[ja] = (ja <= p) ? d0 * 0.125f : 0.f;
        srow[jb] = (jb <= p) ? d1 * 0.125f : 0.f;
    }
}

// ---------------------------------------------------------------------------
// Kernel 6b: per (bh,u): max over [0..p], exp in place, store sum.
// ---------------------------------------------------------------------------
__global__ __launch_bounds__(256)
void attn_softmax(float* __restrict__ scores, const int* __restrict__ m_top,
                  float* __restrict__ sums)
{
    __shared__ float red[256];
    const int gu = blockIdx.x;
    const int p  = m_top[gu];
    const int n  = p + 1;
    float* s = scores + (size_t)gu * L;
    const int tid = threadIdx.x;

    float lmax = -1e30f;
    for (int j = tid; j < n; j += 256) lmax = fmaxf(lmax, s[j]);
    red[tid] = lmax;
    __syncthreads();
    for (int st = 128; st > 0; st >>= 1) {
        if (tid < st) red[tid] = fmaxf(red[tid], red[tid + st]);
        __syncthreads();
    }
    const float M = red[0];
    __syncthreads();

    float lsum = 0.f;
    for (int j = tid; j < n; j += 256) {
        const float e = __expf(s[j] - M);
        s[j] = e;
        lsum += e;
    }
    red[tid] = lsum;
    __syncthreads();
    for (int st = 128; st > 0; st >>= 1) {
        if (tid < st) red[tid] += red[tid + st];
        __syncthreads();
    }
    if (tid == 0) sums[gu] = red[0];
}

// ---------------------------------------------------------------------------
// Kernel 6c: weighted-V partials. Grid (keyChunk=16, bh=16).
// ---------------------------------------------------------------------------
__global__ __launch_bounds__(256)
void attn_wv(const float* __restrict__ scores, const float* __restrict__ V,
             const int* __restrict__ m_top, float* __restrict__ partial,
             int NT)
{
    __shared__ float ssh[45][256];
    __shared__ int   psh[45];

    const int bh = blockIdx.y;
    const int h  = bh & (H - 1);
    const int b  = bh >> 3;
    const int j0 = blockIdx.x * 256;
    const int tid = threadIdx.x;
    const int d   = tid & 63;
    const int jg  = tid >> 6;

    if (tid < NT) psh[tid] = m_top[bh * NT + tid];

    const float* Vb = V + (size_t)b * L * D + h * DH + d;
    const int jbase = j0 + jg * 64;
    float vreg[64];
    #pragma unroll
    for (int i = 0; i < 64; i++) vreg[i] = Vb[(size_t)(jbase + i) * D];

    for (int i = tid; i < NT * 256; i += 256) {
        const int u = i >> 8, j = i & 255;
        ssh[u][j] = scores[(size_t)(bh * NT + u) * L + j0 + j];
    }
    __syncthreads();

    for (int u = 0; u < NT; u++) {
        float acc = 0.f;
        if (psh[u] >= jbase) {
            const float* w = &ssh[u][jg * 64];
            #pragma unroll 8
            for (int i = 0; i < 64; i++) acc += w[i] * vreg[i];
        }
        partial[((size_t)(bh * NT + u) * 64 + blockIdx.x * 4 + jg) * 64 + d] = acc;
    }
}

// ---------------------------------------------------------------------------
// Kernel 6d: reduce partials, divide by sum, overwrite cumsum row.
// ---------------------------------------------------------------------------
__global__ __launch_bounds__(64)
void attn_final(const float* __restrict__ partial, const float* __restrict__ sums,
                const int* __restrict__ m_top, float* __restrict__ out, int NT)
{
    const int gu = blockIdx.x;
    const int bh = gu / NT;
    const int h  = bh & (H - 1);
    const int b  = bh >> 3;
    const int p  = m_top[gu];
    const int d  = threadIdx.x;

    const float* pp = partial + (size_t)gu * 64 * 64 + d;
    float acc = 0.f;
    #pragma unroll 8
    for (int c = 0; c < 64; c++) acc += pp[c * 64];
    out[((size_t)b * L + p) * D + h * DH + d] = acc / sums[gu];
}

// ---------------------------------------------------------------------------
extern "C" void kernel_launch(void* const* d_in, const int* in_sizes, int n_in,
                              void* d_out, int out_size, void* d_ws, size_t ws_size,
                              hipStream_t stream)
{
    const float* queries = (const float*)d_in[0];
    const float* keys    = (const float*)d_in[1];
    const float* values  = (const float*)d_in[2];
    const float* Wq      = (const float*)d_in[3];
    const float* bq      = (const float*)d_in[4];
    const float* Wk      = (const float*)d_in[5];
    const float* bk      = (const float*)d_in[6];
    const float* Wv      = (const float*)d_in[7];
    const float* bv      = (const float*)d_in[8];
    const int*   idx     = (const int*)d_in[9];
    float* out = (float*)d_out;

    const int S  = in_sizes[9] / L;   // sample_k = 45
    const int NT = S;

    const size_t NE = (size_t)B * L * D;
    float* Qb      = (float*)d_ws;
    float* Kb      = Qb + NE;
    float* Vb      = Kb + NE;
    float* m_buf   = Vb + NE;                           // BH*L
    float* cs_part = m_buf + (size_t)BH * L;            // BH*64*DH
    int*   m_top   = (int*)(cs_part + (size_t)BH * 64 * DH);
    float* scores  = (float*)(m_top + 1024);            // BH*NT*L
    float* sums    = scores + (size_t)BH * NT * L;
    float* wv_part = sums + 1024;                       // BH*NT*64*64
    unsigned short* Xp  = (unsigned short*)(wv_part + (size_t)BH * NT * 64 * 64);
    unsigned short* WpT = Xp + (size_t)3 * 8192 * XPW;  // 3*512*K3

    split_x<<<3 * 8192 * 128 / 256, 256, 0, stream>>>(queries, keys, values, Xp);
    split_w<<<dim3(8, 8, 3), 256, 0, stream>>>(Wq, Wk, Wv, WpT);

    gemm_mfma<<<dim3(8192 / 128, 512 / 128, 3), 256, 0, stream>>>(
        Xp, WpT, bq, bk, bv, Qb, Kb, Vb);

    sample_m<<<BH * L / 4, 256, 0, stream>>>(Qb, Kb, idx, m_buf, S);

    topk_kernel<<<BH, 256, 0, stream>>>(m_buf, m_top, NT);

    chunk_sums<<<BH * 64, 64, 0, stream>>>(Vb, cs_part);
    cumsum_write<<<BH * 64, 64, 0, stream>>>(Vb, cs_part, out);

    attn_scores<<<dim3(8, 3, BH), 256, 0, stream>>>(Qb, Kb, m_top, scores, NT);
    attn_softmax<<<BH * NT, 256, 0, stream>>>(scores, m_top, sums);
    attn_wv<<<dim3(16, BH), 256, 0, stream>>>(scores, Vb, m_top, wv_part, NT);
    attn_final<<<BH * NT, 64, 0, stream>>>(wv_part, sums, m_top, out, NT);
}

// Round 5
// 432.580 us; speedup vs baseline: 2.9897x; 1.1358x over previous
//
#include <hip/hip_runtime.h>
#include <math.h>

#define B  2
#define L  4096
#define D  512
#define H  8
#define DH 64
#define BH (B * H)
#define K3 1536          // tripled-K for the bf16 split GEMM
#define XPW 1024         // Xp width: [hi | lo]

typedef short s16x8 __attribute__((ext_vector_type(8)));
typedef float f32x4 __attribute__((ext_vector_type(4)));

#define AS1 __attribute__((address_space(1)))
#define AS3 __attribute__((address_space(3)))

__device__ __forceinline__ void lds_load16(const void* g, void* l) {
    __builtin_amdgcn_global_load_lds((const AS1 unsigned int*)g,
                                     (AS3 unsigned int*)l, 16, 0, 0);
}

__device__ __forceinline__ unsigned short f2bf(float x) {
    union { float f; unsigned u; } v; v.f = x;
    unsigned u = v.u;
    return (unsigned short)((u + 0x7fff + ((u >> 16) & 1)) >> 16);
}
__device__ __forceinline__ float bf2f(unsigned short h) {
    union { float f; unsigned u; } v; v.u = ((unsigned)h) << 16;
    return v.f;
}

// ---------------------------------------------------------------------------
// Prep 1: split X (fp32 8192x512) -> Xp (bf16 8192x1024): [hi | lo]
// ---------------------------------------------------------------------------
__global__ __launch_bounds__(256)
void split_x(const float* __restrict__ q, const float* __restrict__ k,
             const float* __restrict__ v, unsigned short* __restrict__ Xp)
{
    const size_t g = (size_t)blockIdx.x * 256 + threadIdx.x;
    const size_t per = (size_t)8192 * 128;
    const int e = (int)(g / per);
    const size_t rem = g - (size_t)e * per;
    const int m  = (int)(rem >> 7);
    const int kq = (int)(rem & 127) << 2;

    const float* X = (e == 0) ? q : (e == 1) ? k : v;
    const float4 x = *(const float4*)(X + (size_t)m * 512 + kq);

    unsigned short h0 = f2bf(x.x), h1 = f2bf(x.y), h2 = f2bf(x.z), h3 = f2bf(x.w);
    unsigned short l0 = f2bf(x.x - bf2f(h0)), l1 = f2bf(x.y - bf2f(h1));
    unsigned short l2 = f2bf(x.z - bf2f(h2)), l3 = f2bf(x.w - bf2f(h3));

    unsigned short* dst = Xp + (size_t)e * 8192 * XPW + (size_t)m * XPW + kq;
    *(ushort4*)(dst)       = make_ushort4(h0, h1, h2, h3);
    *(ushort4*)(dst + 512) = make_ushort4(l0, l1, l2, l3);
}

// ---------------------------------------------------------------------------
// Prep 2: W (fp32 512x512, [k][n]) -> WpT (bf16 512x1536, [n][k']):
//   k' in [0,512): hi   [512,1024): lo   [1024,1536): hi
// ---------------------------------------------------------------------------
__global__ __launch_bounds__(256)
void split_w(const float* __restrict__ wq, const float* __restrict__ wk,
             const float* __restrict__ wv, unsigned short* __restrict__ WpT)
{
    __shared__ float t[64][65];
    const int e  = blockIdx.z;
    const int k0 = blockIdx.x * 64;
    const int n0 = blockIdx.y * 64;
    const float* W = (e == 0) ? wq : (e == 1) ? wk : wv;
    const int tid = threadIdx.x;

    for (int idx = tid; idx < 64 * 16; idx += 256) {
        const int i = idx >> 4, j4 = (idx & 15) << 2;
        *(float4*)&t[i][j4] = *(const float4*)(W + (size_t)(k0 + i) * 512 + n0 + j4);
    }
    __syncthreads();

    const int n_loc = tid >> 2;
    const int kq    = (tid & 3) << 4;
    unsigned short h[16], l[16];
    #pragma unroll
    for (int tt = 0; tt < 16; tt++) {
        const float x = t[kq + tt][n_loc];
        h[tt] = f2bf(x);
        l[tt] = f2bf(x - bf2f(h[tt]));
    }
    unsigned short* base = WpT + (size_t)e * 512 * K3 + (size_t)(n0 + n_loc) * K3 + k0 + kq;
    #pragma unroll
    for (int g4 = 0; g4 < 4; g4++) {
        ushort4 hv = make_ushort4(h[g4*4], h[g4*4+1], h[g4*4+2], h[g4*4+3]);
        ushort4 lv = make_ushort4(l[g4*4], l[g4*4+1], l[g4*4+2], l[g4*4+3]);
        *(ushort4*)(base + g4*4)        = hv;
        *(ushort4*)(base + 512 + g4*4)  = lv;
        *(ushort4*)(base + 1024 + g4*4) = hv;
    }
}

// ---------------------------------------------------------------------------
// Kernel 1: bf16-split MFMA GEMM. 128x128 tile, BK=32, 4 waves.
// ---------------------------------------------------------------------------
__global__ __launch_bounds__(256)
void gemm_mfma(const unsigned short* __restrict__ Xp,
               const unsigned short* __restrict__ WpT,
               const float* __restrict__ bq, const float* __restrict__ bk,
               const float* __restrict__ bv,
               float* __restrict__ Qo, float* __restrict__ Ko,
               float* __restrict__ Vo)
{
    __shared__ __align__(16) unsigned short smA[4096];
    __shared__ __align__(16) unsigned short smB[4096];

    const int e = blockIdx.z;
    const float* bias = (e == 0) ? bq : (e == 1) ? bk : bv;
    float* C          = (e == 0) ? Qo : (e == 1) ? Ko : Vo;
    const unsigned short* Ag = Xp  + (size_t)e * 8192 * XPW;
    const unsigned short* Bg = WpT + (size_t)e * 512 * K3;

    const int tid  = threadIdx.x;
    const int lane = tid & 63;
    const int wid  = tid >> 6;
    const int wm   = wid & 1;
    const int wn   = wid >> 1;
    const int m0   = blockIdx.x * 128;
    const int n0g  = blockIdx.y * 128;

    const int r1 = tid >> 2;
    const int c8 = (((tid & 3) ^ ((r1 >> 1) & 3)) << 3);
    const unsigned short* agp = Ag + (size_t)(m0 + r1) * XPW + c8;
    const unsigned short* bgp = Bg + (size_t)(n0g + r1) * K3 + c8;
    unsigned short* lA1 = smA + (size_t)(tid & ~63) * 8;
    unsigned short* lA2 = lA1 + 2048;
    unsigned short* lB1 = smB + (size_t)(tid & ~63) * 8;
    unsigned short* lB2 = lB1 + 2048;

    const int r    = lane & 15;
    const int quad = lane >> 4;
    const int swz  = ((quad ^ ((lane >> 1) & 3)) << 4);
    const char* pA = (const char*)smA + (wm * 64 + r) * 64 + swz;
    const char* pB = (const char*)smB + (wn * 64 + r) * 64 + swz;

    f32x4 acc[4][4];
    #pragma unroll
    for (int i = 0; i < 4; i++)
        #pragma unroll
        for (int j = 0; j < 4; j++)
            acc[i][j] = (f32x4){0.f, 0.f, 0.f, 0.f};

    for (int k0 = 0; k0 < K3; k0 += 32) {
        const int kA = (k0 < 512) ? k0 : k0 - 512;
        lds_load16(agp + kA, lA1);
        lds_load16(agp + (size_t)64 * XPW + kA, lA2);
        lds_load16(bgp + k0, lB1);
        lds_load16(bgp + (size_t)64 * K3 + k0, lB2);
        __syncthreads();

        s16x8 af[4], bf[4];
        #pragma unroll
        for (int mt = 0; mt < 4; mt++) af[mt] = *(const s16x8*)(pA + mt * 1024);
        #pragma unroll
        for (int nt = 0; nt < 4; nt++) bf[nt] = *(const s16x8*)(pB + nt * 1024);
        #pragma unroll
        for (int mt = 0; mt < 4; mt++)
            #pragma unroll
            for (int nt = 0; nt < 4; nt++)
                acc[mt][nt] = __builtin_amdgcn_mfma_f32_16x16x32_bf16(
                    af[mt], bf[nt], acc[mt][nt], 0, 0, 0);
        __syncthreads();
    }

    #pragma unroll
    for (int nt = 0; nt < 4; nt++) {
        const int col = n0g + wn * 64 + nt * 16 + r;
        const float bb = bias[col];
        #pragma unroll
        for (int mt = 0; mt < 4; mt++) {
            const int row0 = m0 + wm * 64 + mt * 16 + quad * 4;
            #pragma unroll
            for (int i = 0; i < 4; i++)
                C[(size_t)(row0 + i) * 512 + col] = acc[mt][nt][i] + bb;
        }
    }
}

// ---------------------------------------------------------------------------
// Kernel 2: m[b,h,l] = max_s(q.k_s) - sum_s(q.k_s)/L. Wave per query.
// 4-lane cooperative row loads: lane = (row-slot = lane>>2, quarter = lane&3).
// Each instruction reads 16 rows x 64 B contiguous -> every fetched L2
// sector fully consumed (4x fewer transactions than lane-per-sample).
// Dot completed with 2 shuffles in the 4-lane group; one wave butterfly at
// the end for max/sum.
// ---------------------------------------------------------------------------
__global__ __launch_bounds__(256)
void sample_m(const float* __restrict__ Q, const float* __restrict__ K,
              const int* __restrict__ idx, float* __restrict__ m_out, int S)
{
    __shared__ float qs[4][DH];

    const int lane = threadIdx.x & 63;
    const int wib  = threadIdx.x >> 6;
    const int wid  = blockIdx.x * 4 + wib;
    const int l = wid & (L - 1);
    const int h = (wid >> 12) & (H - 1);
    const int b = wid >> 15;

    qs[wib][lane] = Q[((size_t)b * L + l) * D + h * DH + lane];
    __syncthreads();

    const int r4 = lane >> 2;       // row slot 0..15
    const int c4 = lane & 3;        // quarter of the 256 B head slice

    // q fragment: this lane's 16 dims (float4s c4, c4+4, c4+8, c4+12)
    float4 qf[4];
    {
        const float4* qv = (const float4*)qs[wib];
        #pragma unroll
        for (int i = 0; i < 4; i++) qf[i] = qv[c4 + 4 * i];
    }

    const float* Kb = K + (size_t)b * L * D + h * DH;
    const int* is = idx + (size_t)l * S;

    float vmax = -INFINITY, vsum = 0.f;
    const int passes = (S + 15) >> 4;
    for (int p = 0; p < passes; p++) {
        const int sp = p * 16 + r4;
        const bool ok = sp < S;
        const int j = ok ? is[sp] : 0;
        const float4* Krow = (const float4*)(Kb + (size_t)j * D);
        float dot = 0.f;
        #pragma unroll
        for (int i = 0; i < 4; i++) {
            const float4 kv = Krow[c4 + 4 * i];
            const float4 qq = qf[i];
            dot += qq.x * kv.x + qq.y * kv.y + qq.z * kv.z + qq.w * kv.w;
        }
        dot += __shfl_xor(dot, 1, 64);
        dot += __shfl_xor(dot, 2, 64);   // all 4 lanes now hold the full dot
        if (ok) {
            vmax = fmaxf(vmax, dot);
            if (c4 == 0) vsum += dot;    // count each row once
        }
    }
    #pragma unroll
    for (int off = 32; off; off >>= 1) {
        vmax = fmaxf(vmax, __shfl_xor(vmax, off, 64));
        vsum += __shfl_xor(vsum, off, 64);
    }
    if (lane == 0) m_out[wid] = vmax - vsum * (1.0f / (float)L);
}

// ---------------------------------------------------------------------------
// Kernel 3: top-NT of m over L per (b,h). Iterative argmax in LDS.
// ---------------------------------------------------------------------------
__global__ __launch_bounds__(256)
void topk_kernel(const float* __restrict__ m_in, int* __restrict__ m_top, int NT)
{
    __shared__ float vals[L];
    __shared__ float rv[256];
    __shared__ int   ri[256];
    const float* m = m_in + (size_t)blockIdx.x * L;
    for (int i = threadIdx.x; i < L; i += 256) vals[i] = m[i];
    __syncthreads();

    for (int t = 0; t < NT; t++) {
        float best = -INFINITY; int bi = 0x7fffffff;
        for (int i = threadIdx.x; i < L; i += 256) {
            const float v = vals[i];
            if (v > best) { best = v; bi = i; }
        }
        rv[threadIdx.x] = best; ri[threadIdx.x] = bi;
        __syncthreads();
        for (int sArg = 128; sArg > 0; sArg >>= 1) {
            if (threadIdx.x < sArg) {
                const float v2 = rv[threadIdx.x + sArg];
                const int   i2 = ri[threadIdx.x + sArg];
                if (v2 > rv[threadIdx.x] ||
                    (v2 == rv[threadIdx.x] && i2 < ri[threadIdx.x])) {
                    rv[threadIdx.x] = v2; ri[threadIdx.x] = i2;
                }
            }
            __syncthreads();
        }
        if (threadIdx.x == 0) {
            m_top[blockIdx.x * NT + t] = ri[0];
            vals[ri[0]] = -INFINITY;
        }
        __syncthreads();
    }
}

// ---------------------------------------------------------------------------
// Kernels 4+5: cumsum(V) along L per (b,h,d), chunked scan, chunk = 64.
// ---------------------------------------------------------------------------
#define CH 64
__global__ __launch_bounds__(64)
void chunk_sums(const float* __restrict__ V, float* __restrict__ partial)
{
    const int c = blockIdx.x & 63;
    const int h = (blockIdx.x >> 6) & (H - 1);
    const int b = blockIdx.x >> 9;
    const int d = threadIdx.x;
    const float* base = V + (size_t)b * L * D + h * DH + d;
    float s = 0.f;
    const int l0 = c * CH;
    for (int i = 0; i < CH; i++) s += base[(size_t)(l0 + i) * D];
    partial[((size_t)((b * H + h) * 64 + c)) * DH + d] = s;
}

__global__ __launch_bounds__(64)
void cumsum_write(const float* __restrict__ V, const float* __restrict__ partial,
                  float* __restrict__ out)
{
    const int c = blockIdx.x & 63;
    const int h = (blockIdx.x >> 6) & (H - 1);
    const int b = blockIdx.x >> 9;
    const int d = threadIdx.x;
    const float* base  = V   + (size_t)b * L * D + h * DH + d;
    float*       obase = out + (size_t)b * L * D + h * DH + d;
    const float* pb = partial + (size_t)((b * H + h) * 64) * DH + d;
    float acc = 0.f;
    for (int cc = 0; cc < c; cc++) acc += pb[cc * DH];
    const int l0 = c * CH;
    for (int i = 0; i < CH; i++) {
        acc += base[(size_t)(l0 + i) * D];
        obase[(size_t)(l0 + i) * D] = acc;
    }
}

// ---------------------------------------------------------------------------
// Kernel 6a: raw scores for all (u, j). Grid (keyChunk=8, uGroup=3, bh=16).
// ---------------------------------------------------------------------------
__global__ __launch_bounds__(256)
void attn_scores(const float* __restrict__ Q, const float* __restrict__ K,
                 const int* __restrict__ m_top, float* __restrict__ scores,
                 int NT)
{
    __shared__ float qsh[15][DH];
    __shared__ int   psh[15];

    const int bh = blockIdx.z;
    const int h  = bh & (H - 1);
    const int b  = bh >> 3;
    const int ug = blockIdx.y;
    const int j0 = blockIdx.x * 512;
    const int tid = threadIdx.x;

    for (int i = tid; i < 15 * DH; i += 256) {
        const int u = i >> 6, d = i & 63;
        const int p = m_top[bh * NT + ug * 15 + u];
        if (d == 0) psh[u] = p;
        qsh[u][d] = Q[((size_t)b * L + p) * D + h * DH + d];
    }
    __syncthreads();

    const float* Kb = K + (size_t)b * L * D + h * DH;
    const int ja = j0 + tid;
    const int jb = ja + 256;
    float4 k0[16], k1[16];
    {
        const float4* ra = (const float4*)(Kb + (size_t)ja * D);
        const float4* rb = (const float4*)(Kb + (size_t)jb * D);
        #pragma unroll
        for (int i = 0; i < 16; i++) { k0[i] = ra[i]; k1[i] = rb[i]; }
    }

    for (int u = 0; u < 15; u++) {
        const int p = psh[u];
        const float4* qv = (const float4*)qsh[u];
        float d0 = 0.f, d1 = 0.f;
        #pragma unroll
        for (int i = 0; i < 16; i++) {
            const float4 q4 = qv[i];
            d0 += q4.x * k0[i].x + q4.y * k0[i].y + q4.z * k0[i].z + q4.w * k0[i].w;
            d1 += q4.x * k1[i].x + q4.y * k1[i].y + q4.z * k1[i].z + q4.w * k1[i].w;
        }
        float* srow = scores + (size_t)(bh * NT + ug * 15 + u) * L;
        srow[ja] = (ja <= p) ? d0 * 0.125f : 0.f;
        srow[jb] = (jb <= p) ? d1 * 0.125f : 0.f;
    }
}

// ---------------------------------------------------------------------------
// Kernel 6b: per (bh,u): max over [0..p], exp in place, store sum.
// ---------------------------------------------------------------------------
__global__ __launch_bounds__(256)
void attn_softmax(float* __restrict__ scores, const int* __restrict__ m_top,
                  float* __restrict__ sums)
{
    __shared__ float red[256];
    const int gu = blockIdx.x;
    const int p  = m_top[gu];
    const int n  = p + 1;
    float* s = scores + (size_t)gu * L;
    const int tid = threadIdx.x;

    float lmax = -1e30f;
    for (int j = tid; j < n; j += 256) lmax = fmaxf(lmax, s[j]);
    red[tid] = lmax;
    __syncthreads();
    for (int st = 128; st > 0; st >>= 1) {
        if (tid < st) red[tid] = fmaxf(red[tid], red[tid + st]);
        __syncthreads();
    }
    const float M = red[0];
    __syncthreads();

    float lsum = 0.f;
    for (int j = tid; j < n; j += 256) {
        const float e = __expf(s[j] - M);
        s[j] = e;
        lsum += e;
    }
    red[tid] = lsum;
    __syncthreads();
    for (int st = 128; st > 0; st >>= 1) {
        if (tid < st) red[tid] += red[tid + st];
        __syncthreads();
    }
    if (tid == 0) sums[gu] = red[0];
}

// ---------------------------------------------------------------------------
// Kernel 6c: weighted-V partials. Grid (keyChunk=16, bh=16).
// ---------------------------------------------------------------------------
__global__ __launch_bounds__(256)
void attn_wv(const float* __restrict__ scores, const float* __restrict__ V,
             const int* __restrict__ m_top, float* __restrict__ partial,
             int NT)
{
    __shared__ float ssh[45][256];
    __shared__ int   psh[45];

    const int bh = blockIdx.y;
    const int h  = bh & (H - 1);
    const int b  = bh >> 3;
    const int j0 = blockIdx.x * 256;
    const int tid = threadIdx.x;
    const int d   = tid & 63;
    const int jg  = tid >> 6;

    if (tid < NT) psh[tid] = m_top[bh * NT + tid];

    const float* Vb = V + (size_t)b * L * D + h * DH + d;
    const int jbase = j0 + jg * 64;
    float vreg[64];
    #pragma unroll
    for (int i = 0; i < 64; i++) vreg[i] = Vb[(size_t)(jbase + i) * D];

    for (int i = tid; i < NT * 256; i += 256) {
        const int u = i >> 8, j = i & 255;
        ssh[u][j] = scores[(size_t)(bh * NT + u) * L + j0 + j];
    }
    __syncthreads();

    for (int u = 0; u < NT; u++) {
        float acc = 0.f;
        if (psh[u] >= jbase) {
            const float* w = &ssh[u][jg * 64];
            #pragma unroll 8
            for (int i = 0; i < 64; i++) acc += w[i] * vreg[i];
        }
        partial[((size_t)(bh * NT + u) * 64 + blockIdx.x * 4 + jg) * 64 + d] = acc;
    }
}

// ---------------------------------------------------------------------------
// Kernel 6d: reduce partials, divide by sum, overwrite cumsum row.
// ---------------------------------------------------------------------------
__global__ __launch_bounds__(64)
void attn_final(const float* __restrict__ partial, const float* __restrict__ sums,
                const int* __restrict__ m_top, float* __restrict__ out, int NT)
{
    const int gu = blockIdx.x;
    const int bh = gu / NT;
    const int h  = bh & (H - 1);
    const int b  = bh >> 3;
    const int p  = m_top[gu];
    const int d  = threadIdx.x;

    const float* pp = partial + (size_t)gu * 64 * 64 + d;
    float acc = 0.f;
    #pragma unroll 8
    for (int c = 0; c < 64; c++) acc += pp[c * 64];
    out[((size_t)b * L + p) * D + h * DH + d] = acc / sums[gu];
}

// ---------------------------------------------------------------------------
extern "C" void kernel_launch(void* const* d_in, const int* in_sizes, int n_in,
                              void* d_out, int out_size, void* d_ws, size_t ws_size,
                              hipStream_t stream)
{
    const float* queries = (const float*)d_in[0];
    const float* keys    = (const float*)d_in[1];
    const float* values  = (const float*)d_in[2];
    const float* Wq      = (const float*)d_in[3];
    const float* bq      = (const float*)d_in[4];
    const float* Wk      = (const float*)d_in[5];
    const float* bk      = (const float*)d_in[6];
    const float* Wv      = (const float*)d_in[7];
    const float* bv      = (const float*)d_in[8];
    const int*   idx     = (const int*)d_in[9];
    float* out = (float*)d_out;

    const int S  = in_sizes[9] / L;   // sample_k = 45
    const int NT = S;

    const size_t NE = (size_t)B * L * D;
    float* Qb      = (float*)d_ws;
    float* Kb      = Qb + NE;
    float* Vb      = Kb + NE;
    float* m_buf   = Vb + NE;                           // BH*L
    float* cs_part = m_buf + (size_t)BH * L;            // BH*64*DH
    int*   m_top   = (int*)(cs_part + (size_t)BH * 64 * DH);
    float* scores  = (float*)(m_top + 1024);            // BH*NT*L
    float* sums    = scores + (size_t)BH * NT * L;
    float* wv_part = sums + 1024;                       // BH*NT*64*64
    unsigned short* Xp  = (unsigned short*)(wv_part + (size_t)BH * NT * 64 * 64);
    unsigned short* WpT = Xp + (size_t)3 * 8192 * XPW;  // 3*512*K3

    split_x<<<3 * 8192 * 128 / 256, 256, 0, stream>>>(queries, keys, values, Xp);
    split_w<<<dim3(8, 8, 3), 256, 0, stream>>>(Wq, Wk, Wv, WpT);

    gemm_mfma<<<dim3(8192 / 128, 512 / 128, 3), 256, 0, stream>>>(
        Xp, WpT, bq, bk, bv, Qb, Kb, Vb);

    sample_m<<<BH * L / 4, 256, 0, stream>>>(Qb, Kb, idx, m_buf, S);

    topk_kernel<<<BH, 256, 0, stream>>>(m_buf, m_top, NT);

    chunk_sums<<<BH * 64, 64, 0, stream>>>(Vb, cs_part);
    cumsum_write<<<BH * 64, 64, 0, stream>>>(Vb, cs_part, out);

    attn_scores<<<dim3(8, 3, BH), 256, 0, stream>>>(Qb, Kb, m_top, scores, NT);
    attn_softmax<<<BH * NT, 256, 0, stream>>>(scores, m_top, sums);
    attn_wv<<<dim3(16, BH), 256, 0, stream>>>(scores, Vb, m_top, wv_part, NT);
    attn_final<<<BH * NT, 64, 0, stream>>>(wv_part, sums, m_top, out, NT);
}

// Round 6
// 366.928 us; speedup vs baseline: 3.5246x; 1.1789x over previous
//
#include <hip/hip_runtime.h>
#include <math.h>

#define B  2
#define L  4096
#define D  512
#define H  8
#define DH 64
#define BH (B * H)
#define K3 1536          // tripled-K for the bf16 split GEMM
#define XPW 1024         // Xp width: [hi | lo]

typedef short s16x8 __attribute__((ext_vector_type(8)));
typedef float f32x4 __attribute__((ext_vector_type(4)));

#define AS1 __attribute__((address_space(1)))
#define AS3 __attribute__((address_space(3)))

__device__ __forceinline__ void lds_load16(const void* g, void* l) {
    __builtin_amdgcn_global_load_lds((const AS1 unsigned int*)g,
                                     (AS3 unsigned int*)l, 16, 0, 0);
}

__device__ __forceinline__ unsigned short f2bf(float x) {
    union { float f; unsigned u; } v; v.f = x;
    unsigned u = v.u;
    return (unsigned short)((u + 0x7fff + ((u >> 16) & 1)) >> 16);
}
__device__ __forceinline__ float bf2f(unsigned short h) {
    union { float f; unsigned u; } v; v.u = ((unsigned)h) << 16;
    return v.f;
}

// ---------------------------------------------------------------------------
// Prep 1: split X (fp32 8192x512) -> Xp (bf16 8192x1024): [hi | lo]
// ---------------------------------------------------------------------------
__global__ __launch_bounds__(256)
void split_x(const float* __restrict__ q, const float* __restrict__ k,
             const float* __restrict__ v, unsigned short* __restrict__ Xp)
{
    const size_t g = (size_t)blockIdx.x * 256 + threadIdx.x;
    const size_t per = (size_t)8192 * 128;
    const int e = (int)(g / per);
    const size_t rem = g - (size_t)e * per;
    const int m  = (int)(rem >> 7);
    const int kq = (int)(rem & 127) << 2;

    const float* X = (e == 0) ? q : (e == 1) ? k : v;
    const float4 x = *(const float4*)(X + (size_t)m * 512 + kq);

    unsigned short h0 = f2bf(x.x), h1 = f2bf(x.y), h2 = f2bf(x.z), h3 = f2bf(x.w);
    unsigned short l0 = f2bf(x.x - bf2f(h0)), l1 = f2bf(x.y - bf2f(h1));
    unsigned short l2 = f2bf(x.z - bf2f(h2)), l3 = f2bf(x.w - bf2f(h3));

    unsigned short* dst = Xp + (size_t)e * 8192 * XPW + (size_t)m * XPW + kq;
    *(ushort4*)(dst)       = make_ushort4(h0, h1, h2, h3);
    *(ushort4*)(dst + 512) = make_ushort4(l0, l1, l2, l3);
}

// ---------------------------------------------------------------------------
// Prep 2: W (fp32 512x512, [k][n]) -> WpT (bf16 512x1536, [n][k']):
//   k' in [0,512): hi   [512,1024): lo   [1024,1536): hi
// ---------------------------------------------------------------------------
__global__ __launch_bounds__(256)
void split_w(const float* __restrict__ wq, const float* __restrict__ wk,
             const float* __restrict__ wv, unsigned short* __restrict__ WpT)
{
    __shared__ float t[64][65];
    const int e  = blockIdx.z;
    const int k0 = blockIdx.x * 64;
    const int n0 = blockIdx.y * 64;
    const float* W = (e == 0) ? wq : (e == 1) ? wk : wv;
    const int tid = threadIdx.x;

    for (int idx = tid; idx < 64 * 16; idx += 256) {
        const int i = idx >> 4, j4 = (idx & 15) << 2;
        *(float4*)&t[i][j4] = *(const float4*)(W + (size_t)(k0 + i) * 512 + n0 + j4);
    }
    __syncthreads();

    const int n_loc = tid >> 2;
    const int kq    = (tid & 3) << 4;
    unsigned short h[16], l[16];
    #pragma unroll
    for (int tt = 0; tt < 16; tt++) {
        const float x = t[kq + tt][n_loc];
        h[tt] = f2bf(x);
        l[tt] = f2bf(x - bf2f(h[tt]));
    }
    unsigned short* base = WpT + (size_t)e * 512 * K3 + (size_t)(n0 + n_loc) * K3 + k0 + kq;
    #pragma unroll
    for (int g4 = 0; g4 < 4; g4++) {
        ushort4 hv = make_ushort4(h[g4*4], h[g4*4+1], h[g4*4+2], h[g4*4+3]);
        ushort4 lv = make_ushort4(l[g4*4], l[g4*4+1], l[g4*4+2], l[g4*4+3]);
        *(ushort4*)(base + g4*4)        = hv;
        *(ushort4*)(base + 512 + g4*4)  = lv;
        *(ushort4*)(base + 1024 + g4*4) = hv;
    }
}

// ---------------------------------------------------------------------------
// Kernel 1: bf16-split MFMA GEMM. 128x128 tile, BK=32, 4 waves.
// ---------------------------------------------------------------------------
__global__ __launch_bounds__(256)
void gemm_mfma(const unsigned short* __restrict__ Xp,
               const unsigned short* __restrict__ WpT,
               const float* __restrict__ bq, const float* __restrict__ bk,
               const float* __restrict__ bv,
               float* __restrict__ Qo, float* __restrict__ Ko,
               float* __restrict__ Vo)
{
    __shared__ __align__(16) unsigned short smA[4096];
    __shared__ __align__(16) unsigned short smB[4096];

    const int e = blockIdx.z;
    const float* bias = (e == 0) ? bq : (e == 1) ? bk : bv;
    float* C          = (e == 0) ? Qo : (e == 1) ? Ko : Vo;
    const unsigned short* Ag = Xp  + (size_t)e * 8192 * XPW;
    const unsigned short* Bg = WpT + (size_t)e * 512 * K3;

    const int tid  = threadIdx.x;
    const int lane = tid & 63;
    const int wid  = tid >> 6;
    const int wm   = wid & 1;
    const int wn   = wid >> 1;
    const int m0   = blockIdx.x * 128;
    const int n0g  = blockIdx.y * 128;

    const int r1 = tid >> 2;
    const int c8 = (((tid & 3) ^ ((r1 >> 1) & 3)) << 3);
    const unsigned short* agp = Ag + (size_t)(m0 + r1) * XPW + c8;
    const unsigned short* bgp = Bg + (size_t)(n0g + r1) * K3 + c8;
    unsigned short* lA1 = smA + (size_t)(tid & ~63) * 8;
    unsigned short* lA2 = lA1 + 2048;
    unsigned short* lB1 = smB + (size_t)(tid & ~63) * 8;
    unsigned short* lB2 = lB1 + 2048;

    const int r    = lane & 15;
    const int quad = lane >> 4;
    const int swz  = ((quad ^ ((lane >> 1) & 3)) << 4);
    const char* pA = (const char*)smA + (wm * 64 + r) * 64 + swz;
    const char* pB = (const char*)smB + (wn * 64 + r) * 64 + swz;

    f32x4 acc[4][4];
    #pragma unroll
    for (int i = 0; i < 4; i++)
        #pragma unroll
        for (int j = 0; j < 4; j++)
            acc[i][j] = (f32x4){0.f, 0.f, 0.f, 0.f};

    for (int k0 = 0; k0 < K3; k0 += 32) {
        const int kA = (k0 < 512) ? k0 : k0 - 512;
        lds_load16(agp + kA, lA1);
        lds_load16(agp + (size_t)64 * XPW + kA, lA2);
        lds_load16(bgp + k0, lB1);
        lds_load16(bgp + (size_t)64 * K3 + k0, lB2);
        __syncthreads();

        s16x8 af[4], bf[4];
        #pragma unroll
        for (int mt = 0; mt < 4; mt++) af[mt] = *(const s16x8*)(pA + mt * 1024);
        #pragma unroll
        for (int nt = 0; nt < 4; nt++) bf[nt] = *(const s16x8*)(pB + nt * 1024);
        #pragma unroll
        for (int mt = 0; mt < 4; mt++)
            #pragma unroll
            for (int nt = 0; nt < 4; nt++)
                acc[mt][nt] = __builtin_amdgcn_mfma_f32_16x16x32_bf16(
                    af[mt], bf[nt], acc[mt][nt], 0, 0, 0);
        __syncthreads();
    }

    #pragma unroll
    for (int nt = 0; nt < 4; nt++) {
        const int col = n0g + wn * 64 + nt * 16 + r;
        const float bb = bias[col];
        #pragma unroll
        for (int mt = 0; mt < 4; mt++) {
            const int row0 = m0 + wm * 64 + mt * 16 + quad * 4;
            #pragma unroll
            for (int i = 0; i < 4; i++)
                C[(size_t)(row0 + i) * 512 + col] = acc[mt][nt][i] + bb;
        }
    }
}

// ---------------------------------------------------------------------------
// Kernel 2: m[b,h,l] = max_s(q.k_s) - sum_s(q.k_s)/L. Wave per query.
// 4-lane cooperative row loads.
// ---------------------------------------------------------------------------
__global__ __launch_bounds__(256)
void sample_m(const float* __restrict__ Q, const float* __restrict__ K,
              const int* __restrict__ idx, float* __restrict__ m_out, int S)
{
    __shared__ float qs[4][DH];

    const int lane = threadIdx.x & 63;
    const int wib  = threadIdx.x >> 6;
    const int wid  = blockIdx.x * 4 + wib;
    const int l = wid & (L - 1);
    const int h = (wid >> 12) & (H - 1);
    const int b = wid >> 15;

    qs[wib][lane] = Q[((size_t)b * L + l) * D + h * DH + lane];
    __syncthreads();

    const int r4 = lane >> 2;
    const int c4 = lane & 3;

    float4 qf[4];
    {
        const float4* qv = (const float4*)qs[wib];
        #pragma unroll
        for (int i = 0; i < 4; i++) qf[i] = qv[c4 + 4 * i];
    }

    const float* Kb = K + (size_t)b * L * D + h * DH;
    const int* is = idx + (size_t)l * S;

    float vmax = -INFINITY, vsum = 0.f;
    const int passes = (S + 15) >> 4;
    for (int p = 0; p < passes; p++) {
        const int sp = p * 16 + r4;
        const bool ok = sp < S;
        const int j = ok ? is[sp] : 0;
        const float4* Krow = (const float4*)(Kb + (size_t)j * D);
        float dot = 0.f;
        #pragma unroll
        for (int i = 0; i < 4; i++) {
            const float4 kv = Krow[c4 + 4 * i];
            const float4 qq = qf[i];
            dot += qq.x * kv.x + qq.y * kv.y + qq.z * kv.z + qq.w * kv.w;
        }
        dot += __shfl_xor(dot, 1, 64);
        dot += __shfl_xor(dot, 2, 64);
        if (ok) {
            vmax = fmaxf(vmax, dot);
            if (c4 == 0) vsum += dot;
        }
    }
    #pragma unroll
    for (int off = 32; off; off >>= 1) {
        vmax = fmaxf(vmax, __shfl_xor(vmax, off, 64));
        vsum += __shfl_xor(vsum, off, 64);
    }
    if (lane == 0) m_out[wid] = vmax - vsum * (1.0f / (float)L);
}

// ---------------------------------------------------------------------------
// Kernel 3: top-NT of m over L per (b,h). Iterative argmax in LDS.
// ---------------------------------------------------------------------------
__global__ __launch_bounds__(256)
void topk_kernel(const float* __restrict__ m_in, int* __restrict__ m_top, int NT)
{
    __shared__ float vals[L];
    __shared__ float rv[256];
    __shared__ int   ri[256];
    const float* m = m_in + (size_t)blockIdx.x * L;
    for (int i = threadIdx.x; i < L; i += 256) vals[i] = m[i];
    __syncthreads();

    for (int t = 0; t < NT; t++) {
        float best = -INFINITY; int bi = 0x7fffffff;
        for (int i = threadIdx.x; i < L; i += 256) {
            const float v = vals[i];
            if (v > best) { best = v; bi = i; }
        }
        rv[threadIdx.x] = best; ri[threadIdx.x] = bi;
        __syncthreads();
        for (int sArg = 128; sArg > 0; sArg >>= 1) {
            if (threadIdx.x < sArg) {
                const float v2 = rv[threadIdx.x + sArg];
                const int   i2 = ri[threadIdx.x + sArg];
                if (v2 > rv[threadIdx.x] ||
                    (v2 == rv[threadIdx.x] && i2 < ri[threadIdx.x])) {
                    rv[threadIdx.x] = v2; ri[threadIdx.x] = i2;
                }
            }
            __syncthreads();
        }
        if (threadIdx.x == 0) {
            m_top[blockIdx.x * NT + t] = ri[0];
            vals[ri[0]] = -INFINITY;
        }
        __syncthreads();
    }
}

// ---------------------------------------------------------------------------
// Kernels 4+5: cumsum(V) along L per (b,h,d), chunked scan, chunk = 64.
// ---------------------------------------------------------------------------
#define CH 64
__global__ __launch_bounds__(64)
void chunk_sums(const float* __restrict__ V, float* __restrict__ partial)
{
    const int c = blockIdx.x & 63;
    const int h = (blockIdx.x >> 6) & (H - 1);
    const int b = blockIdx.x >> 9;
    const int d = threadIdx.x;
    const float* base = V + (size_t)b * L * D + h * DH + d;
    float s = 0.f;
    const int l0 = c * CH;
    for (int i = 0; i < CH; i++) s += base[(size_t)(l0 + i) * D];
    partial[((size_t)((b * H + h) * 64 + c)) * DH + d] = s;
}

__global__ __launch_bounds__(64)
void cumsum_write(const float* __restrict__ V, const float* __restrict__ partial,
                  float* __restrict__ out)
{
    const int c = blockIdx.x & 63;
    const int h = (blockIdx.x >> 6) & (H - 1);
    const int b = blockIdx.x >> 9;
    const int d = threadIdx.x;
    const float* base  = V   + (size_t)b * L * D + h * DH + d;
    float*       obase = out + (size_t)b * L * D + h * DH + d;
    const float* pb = partial + (size_t)((b * H + h) * 64) * DH + d;
    float acc = 0.f;
    for (int cc = 0; cc < c; cc++) acc += pb[cc * DH];
    const int l0 = c * CH;
    for (int i = 0; i < CH; i++) {
        acc += base[(size_t)(l0 + i) * D];
        obase[(size_t)(l0 + i) * D] = acc;
    }
}

// ---------------------------------------------------------------------------
// Kernel 6a: raw scores for all (u, j). Grid (keyChunk=8, uGroup=3, bh=16).
// ---------------------------------------------------------------------------
__global__ __launch_bounds__(256)
void attn_scores(const float* __restrict__ Q, const float* __restrict__ K,
                 const int* __restrict__ m_top, float* __restrict__ scores,
                 int NT)
{
    __shared__ float qsh[15][DH];
    __shared__ int   psh[15];

    const int bh = blockIdx.z;
    const int h  = bh & (H - 1);
    const int b  = bh >> 3;
    const int ug = blockIdx.y;
    const int j0 = blockIdx.x * 512;
    const int tid = threadIdx.x;

    for (int i = tid; i < 15 * DH; i += 256) {
        const int u = i >> 6, d = i & 63;
        const int p = m_top[bh * NT + ug * 15 + u];
        if (d == 0) psh[u] = p;
        qsh[u][d] = Q[((size_t)b * L + p) * D + h * DH + d];
    }
    __syncthreads();

    const float* Kb = K + (size_t)b * L * D + h * DH;
    const int ja = j0 + tid;
    const int jb = ja + 256;
    float4 k0[16], k1[16];
    {
        const float4* ra = (const float4*)(Kb + (size_t)ja * D);
        const float4* rb = (const float4*)(Kb + (size_t)jb * D);
        #pragma unroll
        for (int i = 0; i < 16; i++) { k0[i] = ra[i]; k1[i] = rb[i]; }
    }

    for (int u = 0; u < 15; u++) {
        const int p = psh[u];
        const float4* qv = (const float4*)qsh[u];
        float d0 = 0.f, d1 = 0.f;
        #pragma unroll
        for (int i = 0; i < 16; i++) {
            const float4 q4 = qv[i];
            d0 += q4.x * k0[i].x + q4.y * k0[i].y + q4.z * k0[i].z + q4.w * k0[i].w;
            d1 += q4.x * k1[i].x + q4.y * k1[i].y + q4.z * k1[i].z + q4.w * k1[i].w;
        }
        float* srow = scores + (size_t)(bh * NT + ug * 15 + u) * L;
        srow[ja] = (ja <= p) ? d0 * 0.125f : 0.f;
        srow[jb] = (jb <= p) ? d1 * 0.125f : 0.f;
    }
}

// ---------------------------------------------------------------------------
// Kernel 6b: per (bh,u): max over [0..p], exp in place, store sum.
// ---------------------------------------------------------------------------
__global__ __launch_bounds__(256)
void attn_softmax(float* __restrict__ scores, const int* __restrict__ m_top,
                  float* __restrict__ sums)
{
    __shared__ float red[256];
    const int gu = blockIdx.x;
    const int p  = m_top[gu];
    const int n  = p + 1;
    float* s = scores + (size_t)gu * L;
    const int tid = threadIdx.x;

    float lmax = -1e30f;
    for (int j = tid; j < n; j += 256) lmax = fmaxf(lmax, s[j]);
    red[tid] = lmax;
    __syncthreads();
    for (int st = 128; st > 0; st >>= 1) {
        if (tid < st) red[tid] = fmaxf(red[tid], red[tid + st]);
        __syncthreads();
    }
    const float M = red[0];
    __syncthreads();

    float lsum = 0.f;
    for (int j = tid; j < n; j += 256) {
        const float e = __expf(s[j] - M);
        s[j] = e;
        lsum += e;
    }
    red[tid] = lsum;
    __syncthreads();
    for (int st = 128; st > 0; st >>= 1) {
        if (tid < st) red[tid] += red[tid + st];
        __syncthreads();
    }
    if (tid == 0) sums[gu] = red[0];
}

// ---------------------------------------------------------------------------
// Kernel 6c: weighted-V partials. Grid (keyChunk=64, bh=16) = 1024 blocks.
// Thread = (jg = tid>>6 covering 16 keys, d = tid&63). vreg[16]; weights
// ssh[45][64] (11.5 KB). partial[gu][chunk][jg][d] always written.
// ---------------------------------------------------------------------------
__global__ __launch_bounds__(256)
void attn_wv(const float* __restrict__ scores, const float* __restrict__ V,
             const int* __restrict__ m_top, float* __restrict__ partial,
             int NT)
{
    __shared__ float ssh[45][64];
    __shared__ int   psh[45];

    const int bh = blockIdx.y;
    const int h  = bh & (H - 1);
    const int b  = bh >> 3;
    const int chunk = blockIdx.x;
    const int j0 = chunk * 64;
    const int tid = threadIdx.x;
    const int d   = tid & 63;
    const int jg  = tid >> 6;

    if (tid < NT) psh[tid] = m_top[bh * NT + tid];

    // stage V: 16 keys per thread, lane = d (coalesced 256B per instr)
    const float* Vb = V + (size_t)b * L * D + h * DH + d;
    const int jbase = j0 + jg * 16;
    float vreg[16];
    #pragma unroll
    for (int i = 0; i < 16; i++) vreg[i] = Vb[(size_t)(jbase + i) * D];

    // stage exp-weights for all u, this 64-key chunk
    for (int i = tid; i < NT * 64; i += 256) {
        const int u = i >> 6, j = i & 63;
        ssh[u][j] = scores[(size_t)(bh * NT + u) * L + j0 + j];
    }
    __syncthreads();

    float* pbase = partial + ((size_t)bh * NT * 64 + (size_t)chunk) * 256 + jg * 64 + d;
    for (int u = 0; u < NT; u++) {
        float acc = 0.f;
        if (psh[u] >= jbase) {
            const float* w = &ssh[u][jg * 16];
            #pragma unroll
            for (int i = 0; i < 16; i++) acc += w[i] * vreg[i];
        }
        pbase[(size_t)u * 64 * 256] = acc;
    }
}

// ---------------------------------------------------------------------------
// Kernel 6d: reduce 256 partials per (gu,d), divide by sum, overwrite cumsum.
// 256 threads: (q = tid>>6 quarter of chunks, d = tid&63), LDS reduce 4.
// ---------------------------------------------------------------------------
__global__ __launch_bounds__(256)
void attn_final(const float* __restrict__ partial, const float* __restrict__ sums,
                const int* __restrict__ m_top, float* __restrict__ out, int NT)
{
    __shared__ float red[4][64];
    const int gu = blockIdx.x;
    const int bh = gu / NT;
    const int h  = bh & (H - 1);
    const int b  = bh >> 3;
    const int p  = m_top[gu];
    const int tid = threadIdx.x;
    const int d  = tid & 63;
    const int q  = tid >> 6;

    const float* pp = partial + (size_t)gu * 64 * 256 + d;
    float acc = 0.f;
    #pragma unroll 4
    for (int c = q * 16; c < q * 16 + 16; c++) {
        acc += pp[c * 256] + pp[c * 256 + 64] + pp[c * 256 + 128] + pp[c * 256 + 192];
    }
    red[q][d] = acc;
    __syncthreads();
    if (q == 0) {
        const float r = red[0][d] + red[1][d] + red[2][d] + red[3][d];
        out[((size_t)b * L + p) * D + h * DH + d] = r / sums[gu];
    }
}

// ---------------------------------------------------------------------------
extern "C" void kernel_launch(void* const* d_in, const int* in_sizes, int n_in,
                              void* d_out, int out_size, void* d_ws, size_t ws_size,
                              hipStream_t stream)
{
    const float* queries = (const float*)d_in[0];
    const float* keys    = (const float*)d_in[1];
    const float* values  = (const float*)d_in[2];
    const float* Wq      = (const float*)d_in[3];
    const float* bq      = (const float*)d_in[4];
    const float* Wk      = (const float*)d_in[5];
    const float* bk      = (const float*)d_in[6];
    const float* Wv      = (const float*)d_in[7];
    const float* bv      = (const float*)d_in[8];
    const int*   idx     = (const int*)d_in[9];
    float* out = (float*)d_out;

    const int S  = in_sizes[9] / L;   // sample_k = 45
    const int NT = S;

    const size_t NE = (size_t)B * L * D;
    float* Qb      = (float*)d_ws;
    float* Kb      = Qb + NE;
    float* Vb      = Kb + NE;
    float* m_buf   = Vb + NE;                           // BH*L
    float* cs_part = m_buf + (size_t)BH * L;            // BH*64*DH
    int*   m_top   = (int*)(cs_part + (size_t)BH * 64 * DH);
    float* scores  = (float*)(m_top + 1024);            // BH*NT*L
    float* sums    = scores + (size_t)BH * NT * L;
    unsigned short* Xp  = (unsigned short*)(sums + 1024);
    unsigned short* WpT = Xp + (size_t)3 * 8192 * XPW;  // 3*512*K3
    // wv_part (BH*NT*64*256 floats = 47.2 MB) ALIASES Xp (50.3 MB): Xp is
    // dead after gemm_mfma; attn_wv fully rewrites before attn_final reads.
    float* wv_part = (float*)Xp;

    split_x<<<3 * 8192 * 128 / 256, 256, 0, stream>>>(queries, keys, values, Xp);
    split_w<<<dim3(8, 8, 3), 256, 0, stream>>>(Wq, Wk, Wv, WpT);

    gemm_mfma<<<dim3(8192 / 128, 512 / 128, 3), 256, 0, stream>>>(
        Xp, WpT, bq, bk, bv, Qb, Kb, Vb);

    sample_m<<<BH * L / 4, 256, 0, stream>>>(Qb, Kb, idx, m_buf, S);

    topk_kernel<<<BH, 256, 0, stream>>>(m_buf, m_top, NT);

    chunk_sums<<<BH * 64, 64, 0, stream>>>(Vb, cs_part);
    cumsum_write<<<BH * 64, 64, 0, stream>>>(Vb, cs_part, out);

    attn_scores<<<dim3(8, 3, BH), 256, 0, stream>>>(Qb, Kb, m_top, scores, NT);
    attn_softmax<<<BH * NT, 256, 0, stream>>>(scores, m_top, sums);
    attn_wv<<<dim3(64, BH), 256, 0, stream>>>(scores, Vb, m_top, wv_part, NT);
    attn_final<<<BH * NT, 256, 0, stream>>>(wv_part, sums, m_top, out, NT);
}

// Round 7
// 297.994 us; speedup vs baseline: 4.3400x; 1.2313x over previous
//
#include <hip/hip_runtime.h>
#include <math.h>

#define B  2
#define L  4096
#define D  512
#define H  8
#define DH 64
#define BH (B * H)
#define K3 1536          // tripled-K for the bf16 split GEMM
#define XPW 1024         // Xp width: [hi | lo]

typedef short s16x8 __attribute__((ext_vector_type(8)));
typedef float f32x4 __attribute__((ext_vector_type(4)));

#define AS1 __attribute__((address_space(1)))
#define AS3 __attribute__((address_space(3)))

__device__ __forceinline__ void lds_load16(const void* g, void* l) {
    __builtin_amdgcn_global_load_lds((const AS1 unsigned int*)g,
                                     (AS3 unsigned int*)l, 16, 0, 0);
}

__device__ __forceinline__ unsigned short f2bf(float x) {
    union { float f; unsigned u; } v; v.f = x;
    unsigned u = v.u;
    return (unsigned short)((u + 0x7fff + ((u >> 16) & 1)) >> 16);
}
__device__ __forceinline__ float bf2f(unsigned short h) {
    union { float f; unsigned u; } v; v.u = ((unsigned)h) << 16;
    return v.f;
}

// ---------------------------------------------------------------------------
// Prep 1: split X (fp32 8192x512) -> Xp (bf16 8192x1024): [hi | lo]
// ---------------------------------------------------------------------------
__global__ __launch_bounds__(256)
void split_x(const float* __restrict__ q, const float* __restrict__ k,
             const float* __restrict__ v, unsigned short* __restrict__ Xp)
{
    const size_t g = (size_t)blockIdx.x * 256 + threadIdx.x;
    const size_t per = (size_t)8192 * 128;
    const int e = (int)(g / per);
    const size_t rem = g - (size_t)e * per;
    const int m  = (int)(rem >> 7);
    const int kq = (int)(rem & 127) << 2;

    const float* X = (e == 0) ? q : (e == 1) ? k : v;
    const float4 x = *(const float4*)(X + (size_t)m * 512 + kq);

    unsigned short h0 = f2bf(x.x), h1 = f2bf(x.y), h2 = f2bf(x.z), h3 = f2bf(x.w);
    unsigned short l0 = f2bf(x.x - bf2f(h0)), l1 = f2bf(x.y - bf2f(h1));
    unsigned short l2 = f2bf(x.z - bf2f(h2)), l3 = f2bf(x.w - bf2f(h3));

    unsigned short* dst = Xp + (size_t)e * 8192 * XPW + (size_t)m * XPW + kq;
    *(ushort4*)(dst)       = make_ushort4(h0, h1, h2, h3);
    *(ushort4*)(dst + 512) = make_ushort4(l0, l1, l2, l3);
}

// ---------------------------------------------------------------------------
// Prep 2: W (fp32 512x512, [k][n]) -> WpT (bf16 512x1536, [n][k']):
//   k' in [0,512): hi   [512,1024): lo   [1024,1536): hi
// ---------------------------------------------------------------------------
__global__ __launch_bounds__(256)
void split_w(const float* __restrict__ wq, const float* __restrict__ wk,
             const float* __restrict__ wv, unsigned short* __restrict__ WpT)
{
    __shared__ float t[64][65];
    const int e  = blockIdx.z;
    const int k0 = blockIdx.x * 64;
    const int n0 = blockIdx.y * 64;
    const float* W = (e == 0) ? wq : (e == 1) ? wk : wv;
    const int tid = threadIdx.x;

    for (int idx = tid; idx < 64 * 16; idx += 256) {
        const int i = idx >> 4, j4 = (idx & 15) << 2;
        *(float4*)&t[i][j4] = *(const float4*)(W + (size_t)(k0 + i) * 512 + n0 + j4);
    }
    __syncthreads();

    const int n_loc = tid >> 2;
    const int kq    = (tid & 3) << 4;
    unsigned short h[16], l[16];
    #pragma unroll
    for (int tt = 0; tt < 16; tt++) {
        const float x = t[kq + tt][n_loc];
        h[tt] = f2bf(x);
        l[tt] = f2bf(x - bf2f(h[tt]));
    }
    unsigned short* base = WpT + (size_t)e * 512 * K3 + (size_t)(n0 + n_loc) * K3 + k0 + kq;
    #pragma unroll
    for (int g4 = 0; g4 < 4; g4++) {
        ushort4 hv = make_ushort4(h[g4*4], h[g4*4+1], h[g4*4+2], h[g4*4+3]);
        ushort4 lv = make_ushort4(l[g4*4], l[g4*4+1], l[g4*4+2], l[g4*4+3]);
        *(ushort4*)(base + g4*4)        = hv;
        *(ushort4*)(base + 512 + g4*4)  = lv;
        *(ushort4*)(base + 1024 + g4*4) = hv;
    }
}

// ---------------------------------------------------------------------------
// Kernel 1: bf16-split MFMA GEMM. 128x128 tile, BK=32, 4 waves.
// ---------------------------------------------------------------------------
__global__ __launch_bounds__(256)
void gemm_mfma(const unsigned short* __restrict__ Xp,
               const unsigned short* __restrict__ WpT,
               const float* __restrict__ bq, const float* __restrict__ bk,
               const float* __restrict__ bv,
               float* __restrict__ Qo, float* __restrict__ Ko,
               float* __restrict__ Vo)
{
    __shared__ __align__(16) unsigned short smA[4096];
    __shared__ __align__(16) unsigned short smB[4096];

    const int e = blockIdx.z;
    const float* bias = (e == 0) ? bq : (e == 1) ? bk : bv;
    float* C          = (e == 0) ? Qo : (e == 1) ? Ko : Vo;
    const unsigned short* Ag = Xp  + (size_t)e * 8192 * XPW;
    const unsigned short* Bg = WpT + (size_t)e * 512 * K3;

    const int tid  = threadIdx.x;
    const int lane = tid & 63;
    const int wid  = tid >> 6;
    const int wm   = wid & 1;
    const int wn   = wid >> 1;
    const int m0   = blockIdx.x * 128;
    const int n0g  = blockIdx.y * 128;

    const int r1 = tid >> 2;
    const int c8 = (((tid & 3) ^ ((r1 >> 1) & 3)) << 3);
    const unsigned short* agp = Ag + (size_t)(m0 + r1) * XPW + c8;
    const unsigned short* bgp = Bg + (size_t)(n0g + r1) * K3 + c8;
    unsigned short* lA1 = smA + (size_t)(tid & ~63) * 8;
    unsigned short* lA2 = lA1 + 2048;
    unsigned short* lB1 = smB + (size_t)(tid & ~63) * 8;
    unsigned short* lB2 = lB1 + 2048;

    const int r    = lane & 15;
    const int quad = lane >> 4;
    const int swz  = ((quad ^ ((lane >> 1) & 3)) << 4);
    const char* pA = (const char*)smA + (wm * 64 + r) * 64 + swz;
    const char* pB = (const char*)smB + (wn * 64 + r) * 64 + swz;

    f32x4 acc[4][4];
    #pragma unroll
    for (int i = 0; i < 4; i++)
        #pragma unroll
        for (int j = 0; j < 4; j++)
            acc[i][j] = (f32x4){0.f, 0.f, 0.f, 0.f};

    for (int k0 = 0; k0 < K3; k0 += 32) {
        const int kA = (k0 < 512) ? k0 : k0 - 512;
        lds_load16(agp + kA, lA1);
        lds_load16(agp + (size_t)64 * XPW + kA, lA2);
        lds_load16(bgp + k0, lB1);
        lds_load16(bgp + (size_t)64 * K3 + k0, lB2);
        __syncthreads();

        s16x8 af[4], bf[4];
        #pragma unroll
        for (int mt = 0; mt < 4; mt++) af[mt] = *(const s16x8*)(pA + mt * 1024);
        #pragma unroll
        for (int nt = 0; nt < 4; nt++) bf[nt] = *(const s16x8*)(pB + nt * 1024);
        #pragma unroll
        for (int mt = 0; mt < 4; mt++)
            #pragma unroll
            for (int nt = 0; nt < 4; nt++)
                acc[mt][nt] = __builtin_amdgcn_mfma_f32_16x16x32_bf16(
                    af[mt], bf[nt], acc[mt][nt], 0, 0, 0);
        __syncthreads();
    }

    #pragma unroll
    for (int nt = 0; nt < 4; nt++) {
        const int col = n0g + wn * 64 + nt * 16 + r;
        const float bb = bias[col];
        #pragma unroll
        for (int mt = 0; mt < 4; mt++) {
            const int row0 = m0 + wm * 64 + mt * 16 + quad * 4;
            #pragma unroll
            for (int i = 0; i < 4; i++)
                C[(size_t)(row0 + i) * 512 + col] = acc[mt][nt][i] + bb;
        }
    }
}

// ---------------------------------------------------------------------------
// Kernel 2: m[b,h,l] = max_s(q.k_s) - sum_s(q.k_s)/L. Wave per query.
// 4-lane cooperative row loads.
// ---------------------------------------------------------------------------
__global__ __launch_bounds__(256)
void sample_m(const float* __restrict__ Q, const float* __restrict__ K,
              const int* __restrict__ idx, float* __restrict__ m_out, int S)
{
    __shared__ float qs[4][DH];

    const int lane = threadIdx.x & 63;
    const int wib  = threadIdx.x >> 6;
    const int wid  = blockIdx.x * 4 + wib;
    const int l = wid & (L - 1);
    const int h = (wid >> 12) & (H - 1);
    const int b = wid >> 15;

    qs[wib][lane] = Q[((size_t)b * L + l) * D + h * DH + lane];
    __syncthreads();

    const int r4 = lane >> 2;
    const int c4 = lane & 3;

    float4 qf[4];
    {
        const float4* qv = (const float4*)qs[wib];
        #pragma unroll
        for (int i = 0; i < 4; i++) qf[i] = qv[c4 + 4 * i];
    }

    const float* Kb = K + (size_t)b * L * D + h * DH;
    const int* is = idx + (size_t)l * S;

    float vmax = -INFINITY, vsum = 0.f;
    const int passes = (S + 15) >> 4;
    for (int p = 0; p < passes; p++) {
        const int sp = p * 16 + r4;
        const bool ok = sp < S;
        const int j = ok ? is[sp] : 0;
        const float4* Krow = (const float4*)(Kb + (size_t)j * D);
        float dot = 0.f;
        #pragma unroll
        for (int i = 0; i < 4; i++) {
            const float4 kv = Krow[c4 + 4 * i];
            const float4 qq = qf[i];
            dot += qq.x * kv.x + qq.y * kv.y + qq.z * kv.z + qq.w * kv.w;
        }
        dot += __shfl_xor(dot, 1, 64);
        dot += __shfl_xor(dot, 2, 64);
        if (ok) {
            vmax = fmaxf(vmax, dot);
            if (c4 == 0) vsum += dot;
        }
    }
    #pragma unroll
    for (int off = 32; off; off >>= 1) {
        vmax = fmaxf(vmax, __shfl_xor(vmax, off, 64));
        vsum += __shfl_xor(vsum, off, 64);
    }
    if (lane == 0) m_out[wid] = vmax - vsum * (1.0f / (float)L);
}

// ---------------------------------------------------------------------------
// Kernel 3: exact top-NT via 4-level byte radix-select. One block per (b,h).
// Values held in registers (16/thread); ~18 barriers total vs ~500 for
// iterative argmax. Ties resolved to lowest index (matches top_k stability;
// only the selected SET affects the output).
// ---------------------------------------------------------------------------
__global__ __launch_bounds__(256)
void topk_kernel(const float* __restrict__ m_in, int* __restrict__ m_top, int NT)
{
    __shared__ unsigned hist[256];
    __shared__ unsigned sfx[257];
    __shared__ int sh_b, sh_rem;
    __shared__ int cnt_gt, cnt_eq;
    __shared__ int eqlist[128];

    const float* m = m_in + (size_t)blockIdx.x * L;
    const int tid = threadIdx.x;
    int* out = m_top + blockIdx.x * NT;

    // load 16 values into registers as order-preserving sortable uints
    unsigned uv[16];
    #pragma unroll
    for (int k = 0; k < 16; k++) {
        const float f = m[tid + k * 256];
        const unsigned x = __float_as_uint(f);
        uv[k] = (x & 0x80000000u) ? ~x : (x | 0x80000000u);
    }

    unsigned prefix = 0;
    int rem = NT;

    for (int level = 0; level < 4; level++) {
        const int shift = 24 - level * 8;
        hist[tid] = 0;
        if (tid == 0) { cnt_gt = 0; cnt_eq = 0; }
        __syncthreads();
        #pragma unroll
        for (int k = 0; k < 16; k++) {
            const bool part = (level == 0) || ((uv[k] >> (shift + 8)) == prefix);
            if (part) atomicAdd(&hist[(uv[k] >> shift) & 255], 1u);
        }
        __syncthreads();
        if (tid < 64) {
            const unsigned s0 = hist[4*tid+0], s1 = hist[4*tid+1];
            const unsigned s2 = hist[4*tid+2], s3 = hist[4*tid+3];
            const unsigned loc = s0 + s1 + s2 + s3;
            unsigned suf = loc;
            #pragma unroll
            for (int off = 1; off < 64; off <<= 1) {
                const unsigned t = __shfl_down(suf, off, 64);
                if (tid + off < 64) suf += t;
            }
            const unsigned tail = suf - loc;
            sfx[4*tid+3] = tail + s3;
            sfx[4*tid+2] = tail + s3 + s2;
            sfx[4*tid+1] = tail + s3 + s2 + s1;
            sfx[4*tid+0] = suf;
            if (tid == 0) sfx[256] = 0;
        }
        __syncthreads();
        if (sfx[tid + 1] < (unsigned)rem && (unsigned)rem <= sfx[tid]) {
            sh_b   = tid;
            sh_rem = rem - (int)sfx[tid + 1];
        }
        __syncthreads();
        prefix = (prefix << 8) | (unsigned)sh_b;
        rem    = sh_rem;
        __syncthreads();
    }

    const unsigned T = prefix;           // exact sortable value of the NT-th largest
    const int n_gt = NT - rem;           // count strictly greater

    #pragma unroll
    for (int k = 0; k < 16; k++) {
        if (uv[k] > T) {
            const int pos = atomicAdd(&cnt_gt, 1);
            out[pos] = tid + k * 256;
        } else if (uv[k] == T) {
            const int pos = atomicAdd(&cnt_eq, 1);
            if (pos < 128) eqlist[pos] = tid + k * 256;
        }
    }
    __syncthreads();
    if (tid == 0) {
        int n = cnt_eq < 128 ? cnt_eq : 128;
        for (int r = 0; r < rem; r++) {          // take 'rem' lowest indices
            int best = 0x7fffffff, bi = 0;
            for (int i = 0; i < n; i++)
                if (eqlist[i] < best) { best = eqlist[i]; bi = i; }
            out[n_gt + r] = best;
            eqlist[bi] = 0x7fffffff;
        }
    }
}

// ---------------------------------------------------------------------------
// Kernels 4+5: cumsum(V) along L per (b,h,d), chunked scan, chunk = 64.
// ---------------------------------------------------------------------------
#define CH 64
__global__ __launch_bounds__(64)
void chunk_sums(const float* __restrict__ V, float* __restrict__ partial)
{
    const int c = blockIdx.x & 63;
    const int h = (blockIdx.x >> 6) & (H - 1);
    const int b = blockIdx.x >> 9;
    const int d = threadIdx.x;
    const float* base = V + (size_t)b * L * D + h * DH + d;
    float s = 0.f;
    const int l0 = c * CH;
    for (int i = 0; i < CH; i++) s += base[(size_t)(l0 + i) * D];
    partial[((size_t)((b * H + h) * 64 + c)) * DH + d] = s;
}

__global__ __launch_bounds__(64)
void cumsum_write(const float* __restrict__ V, const float* __restrict__ partial,
                  float* __restrict__ out)
{
    const int c = blockIdx.x & 63;
    const int h = (blockIdx.x >> 6) & (H - 1);
    const int b = blockIdx.x >> 9;
    const int d = threadIdx.x;
    const float* base  = V   + (size_t)b * L * D + h * DH + d;
    float*       obase = out + (size_t)b * L * D + h * DH + d;
    const float* pb = partial + (size_t)((b * H + h) * 64) * DH + d;
    float acc = 0.f;
    for (int cc = 0; cc < c; cc++) acc += pb[cc * DH];
    const int l0 = c * CH;
    for (int i = 0; i < CH; i++) {
        acc += base[(size_t)(l0 + i) * D];
        obase[(size_t)(l0 + i) * D] = acc;
    }
}

// ---------------------------------------------------------------------------
// Kernel 6a: raw scores for all (u, j). Grid (keyChunk=8, uGroup=3, bh=16).
// ---------------------------------------------------------------------------
__global__ __launch_bounds__(256)
void attn_scores(const float* __restrict__ Q, const float* __restrict__ K,
                 const int* __restrict__ m_top, float* __restrict__ scores,
                 int NT)
{
    __shared__ float qsh[15][DH];
    __shared__ int   psh[15];

    const int bh = blockIdx.z;
    const int h  = bh & (H - 1);
    const int b  = bh >> 3;
    const int ug = blockIdx.y;
    const int j0 = blockIdx.x * 512;
    const int tid = threadIdx.x;

    for (int i = tid; i < 15 * DH; i += 256) {
        const int u = i >> 6, d = i & 63;
        const int p = m_top[bh * NT + ug * 15 + u];
        if (d == 0) psh[u] = p;
        qsh[u][d] = Q[((size_t)b * L + p) * D + h * DH + d];
    }
    __syncthreads();

    const float* Kb = K + (size_t)b * L * D + h * DH;
    const int ja = j0 + tid;
    const int jb = ja + 256;
    float4 k0[16], k1[16];
    {
        const float4* ra = (const float4*)(Kb + (size_t)ja * D);
        const float4* rb = (const float4*)(Kb + (size_t)jb * D);
        #pragma unroll
        for (int i = 0; i < 16; i++) { k0[i] = ra[i]; k1[i] = rb[i]; }
    }

    for (int u = 0; u < 15; u++) {
        const int p = psh[u];
        const float4* qv = (const float4*)qsh[u];
        float d0 = 0.f, d1 = 0.f;
        #pragma unroll
        for (int i = 0; i < 16; i++) {
            const float4 q4 = qv[i];
            d0 += q4.x * k0[i].x + q4.y * k0[i].y + q4.z * k0[i].z + q4.w * k0[i].w;
            d1 += q4.x * k1[i].x + q4.y * k1[i].y + q4.z * k1[i].z + q4.w * k1[i].w;
        }
        float* srow = scores + (size_t)(bh * NT + ug * 15 + u) * L;
        srow[ja] = (ja <= p) ? d0 * 0.125f : 0.f;
        srow[jb] = (jb <= p) ? d1 * 0.125f : 0.f;
    }
}

// ---------------------------------------------------------------------------
// Kernel 6b: per (bh,u): max over [0..p], exp in place, store sum.
// ---------------------------------------------------------------------------
__global__ __launch_bounds__(256)
void attn_softmax(float* __restrict__ scores, const int* __restrict__ m_top,
                  float* __restrict__ sums)
{
    __shared__ float red[256];
    const int gu = blockIdx.x;
    const int p  = m_top[gu];
    const int n  = p + 1;
    float* s = scores + (size_t)gu * L;
    const int tid = threadIdx.x;

    float lmax = -1e30f;
    for (int j = tid; j < n; j += 256) lmax = fmaxf(lmax, s[j]);
    red[tid] = lmax;
    __syncthreads();
    for (int st = 128; st > 0; st >>= 1) {
        if (tid < st) red[tid] = fmaxf(red[tid], red[tid + st]);
        __syncthreads();
    }
    const float M = red[0];
    __syncthreads();

    float lsum = 0.f;
    for (int j = tid; j < n; j += 256) {
        const float e = __expf(s[j] - M);
        s[j] = e;
        lsum += e;
    }
    red[tid] = lsum;
    __syncthreads();
    for (int st = 128; st > 0; st >>= 1) {
        if (tid < st) red[tid] += red[tid + st];
        __syncthreads();
    }
    if (tid == 0) sums[gu] = red[0];
}

// ---------------------------------------------------------------------------
// Kernel 6c: weighted-V partials. Grid (keyChunk=64, bh=16) = 1024 blocks.
// ---------------------------------------------------------------------------
__global__ __launch_bounds__(256)
void attn_wv(const float* __restrict__ scores, const float* __restrict__ V,
             const int* __restrict__ m_top, float* __restrict__ partial,
             int NT)
{
    __shared__ float ssh[45][64];
    __shared__ int   psh[45];

    const int bh = blockIdx.y;
    const int h  = bh & (H - 1);
    const int b  = bh >> 3;
    const int chunk = blockIdx.x;
    const int j0 = chunk * 64;
    const int tid = threadIdx.x;
    const int d   = tid & 63;
    const int jg  = tid >> 6;

    if (tid < NT) psh[tid] = m_top[bh * NT + tid];

    const float* Vb = V + (size_t)b * L * D + h * DH + d;
    const int jbase = j0 + jg * 16;
    float vreg[16];
    #pragma unroll
    for (int i = 0; i < 16; i++) vreg[i] = Vb[(size_t)(jbase + i) * D];

    for (int i = tid; i < NT * 64; i += 256) {
        const int u = i >> 6, j = i & 63;
        ssh[u][j] = scores[(size_t)(bh * NT + u) * L + j0 + j];
    }
    __syncthreads();

    float* pbase = partial + ((size_t)bh * NT * 64 + (size_t)chunk) * 256 + jg * 64 + d;
    for (int u = 0; u < NT; u++) {
        float acc = 0.f;
        if (psh[u] >= jbase) {
            const float* w = &ssh[u][jg * 16];
            #pragma unroll
            for (int i = 0; i < 16; i++) acc += w[i] * vreg[i];
        }
        pbase[(size_t)u * 64 * 256] = acc;
    }
}

// ---------------------------------------------------------------------------
// Kernel 6d: reduce 256 partials per (gu,d), divide by sum, overwrite cumsum.
// ---------------------------------------------------------------------------
__global__ __launch_bounds__(256)
void attn_final(const float* __restrict__ partial, const float* __restrict__ sums,
                const int* __restrict__ m_top, float* __restrict__ out, int NT)
{
    __shared__ float red[4][64];
    const int gu = blockIdx.x;
    const int bh = gu / NT;
    const int h  = bh & (H - 1);
    const int b  = bh >> 3;
    const int p  = m_top[gu];
    const int tid = threadIdx.x;
    const int d  = tid & 63;
    const int q  = tid >> 6;

    const float* pp = partial + (size_t)gu * 64 * 256 + d;
    float acc = 0.f;
    #pragma unroll 4
    for (int c = q * 16; c < q * 16 + 16; c++) {
        acc += pp[c * 256] + pp[c * 256 + 64] + pp[c * 256 + 128] + pp[c * 256 + 192];
    }
    red[q][d] = acc;
    __syncthreads();
    if (q == 0) {
        const float r = red[0][d] + red[1][d] + red[2][d] + red[3][d];
        out[((size_t)b * L + p) * D + h * DH + d] = r / sums[gu];
    }
}

// ---------------------------------------------------------------------------
extern "C" void kernel_launch(void* const* d_in, const int* in_sizes, int n_in,
                              void* d_out, int out_size, void* d_ws, size_t ws_size,
                              hipStream_t stream)
{
    const float* queries = (const float*)d_in[0];
    const float* keys    = (const float*)d_in[1];
    const float* values  = (const float*)d_in[2];
    const float* Wq      = (const float*)d_in[3];
    const float* bq      = (const float*)d_in[4];
    const float* Wk      = (const float*)d_in[5];
    const float* bk      = (const float*)d_in[6];
    const float* Wv      = (const float*)d_in[7];
    const float* bv      = (const float*)d_in[8];
    const int*   idx     = (const int*)d_in[9];
    float* out = (float*)d_out;

    const int S  = in_sizes[9] / L;   // sample_k = 45
    const int NT = S;

    const size_t NE = (size_t)B * L * D;
    float* Qb      = (float*)d_ws;
    float* Kb      = Qb + NE;
    float* Vb      = Kb + NE;
    float* m_buf   = Vb + NE;                           // BH*L
    float* cs_part = m_buf + (size_t)BH * L;            // BH*64*DH
    int*   m_top   = (int*)(cs_part + (size_t)BH * 64 * DH);
    float* scores  = (float*)(m_top + 1024);            // BH*NT*L
    float* sums    = scores + (size_t)BH * NT * L;
    unsigned short* Xp  = (unsigned short*)(sums + 1024);
    unsigned short* WpT = Xp + (size_t)3 * 8192 * XPW;  // 3*512*K3
    // wv_part (BH*NT*64*256 floats = 47.2 MB) ALIASES Xp (50.3 MB): Xp is
    // dead after gemm_mfma; attn_wv fully rewrites before attn_final reads.
    float* wv_part = (float*)Xp;

    split_x<<<3 * 8192 * 128 / 256, 256, 0, stream>>>(queries, keys, values, Xp);
    split_w<<<dim3(8, 8, 3), 256, 0, stream>>>(Wq, Wk, Wv, WpT);

    gemm_mfma<<<dim3(8192 / 128, 512 / 128, 3), 256, 0, stream>>>(
        Xp, WpT, bq, bk, bv, Qb, Kb, Vb);

    sample_m<<<BH * L / 4, 256, 0, stream>>>(Qb, Kb, idx, m_buf, S);

    topk_kernel<<<BH, 256, 0, stream>>>(m_buf, m_top, NT);

    chunk_sums<<<BH * 64, 64, 0, stream>>>(Vb, cs_part);
    cumsum_write<<<BH * 64, 64, 0, stream>>>(Vb, cs_part, out);

    attn_scores<<<dim3(8, 3, BH), 256, 0, stream>>>(Qb, Kb, m_top, scores, NT);
    attn_softmax<<<BH * NT, 256, 0, stream>>>(scores, m_top, sums);
    attn_wv<<<dim3(64, BH), 256, 0, stream>>>(scores, Vb, m_top, wv_part, NT);
    attn_final<<<BH * NT, 256, 0, stream>>>(wv_part, sums, m_top, out, NT);
}

// Round 8
// 278.830 us; speedup vs baseline: 4.6382x; 1.0687x over previous
//
#include <hip/hip_runtime.h>
#include <math.h>

#define B  2
#define L  4096
#define D  512
#define H  8
#define DH 64
#define BH (B * H)
#define K3 1536          // tripled-K for the bf16 split GEMM (Q,K)
#define XPW 1024         // Xp width: [hi | lo]

typedef short s16x8 __attribute__((ext_vector_type(8)));
typedef float f32x4 __attribute__((ext_vector_type(4)));

#define AS1 __attribute__((address_space(1)))
#define AS3 __attribute__((address_space(3)))

__device__ __forceinline__ void lds_load16(const void* g, void* l) {
    __builtin_amdgcn_global_load_lds((const AS1 unsigned int*)g,
                                     (AS3 unsigned int*)l, 16, 0, 0);
}

__device__ __forceinline__ unsigned short f2bf(float x) {
    union { float f; unsigned u; } v; v.f = x;
    unsigned u = v.u;
    return (unsigned short)((u + 0x7fff + ((u >> 16) & 1)) >> 16);
}
__device__ __forceinline__ float bf2f(unsigned short h) {
    union { float f; unsigned u; } v; v.u = ((unsigned)h) << 16;
    return v.f;
}

// ---------------------------------------------------------------------------
// Prep 1: split X (fp32 8192x512) -> Xp (bf16 8192x1024): [hi | lo]
// V (e==2) needs only hi (bf16 GEMM): skip lo store.
// ---------------------------------------------------------------------------
__global__ __launch_bounds__(256)
void split_x(const float* __restrict__ q, const float* __restrict__ k,
             const float* __restrict__ v, unsigned short* __restrict__ Xp)
{
    const size_t g = (size_t)blockIdx.x * 256 + threadIdx.x;
    const size_t per = (size_t)8192 * 128;
    const int e = (int)(g / per);
    const size_t rem = g - (size_t)e * per;
    const int m  = (int)(rem >> 7);
    const int kq = (int)(rem & 127) << 2;

    const float* X = (e == 0) ? q : (e == 1) ? k : v;
    const float4 x = *(const float4*)(X + (size_t)m * 512 + kq);

    unsigned short h0 = f2bf(x.x), h1 = f2bf(x.y), h2 = f2bf(x.z), h3 = f2bf(x.w);

    unsigned short* dst = Xp + (size_t)e * 8192 * XPW + (size_t)m * XPW + kq;
    *(ushort4*)(dst) = make_ushort4(h0, h1, h2, h3);
    if (e != 2) {
        unsigned short l0 = f2bf(x.x - bf2f(h0)), l1 = f2bf(x.y - bf2f(h1));
        unsigned short l2 = f2bf(x.z - bf2f(h2)), l3 = f2bf(x.w - bf2f(h3));
        *(ushort4*)(dst + 512) = make_ushort4(l0, l1, l2, l3);
    }
}

// ---------------------------------------------------------------------------
// Prep 2: W (fp32 512x512, [k][n]) -> WpT (bf16 512x1536, [n][k']):
//   k' in [0,512): hi   [512,1024): lo   [1024,1536): hi
// ---------------------------------------------------------------------------
__global__ __launch_bounds__(256)
void split_w(const float* __restrict__ wq, const float* __restrict__ wk,
             const float* __restrict__ wv, unsigned short* __restrict__ WpT)
{
    __shared__ float t[64][65];
    const int e  = blockIdx.z;
    const int k0 = blockIdx.x * 64;
    const int n0 = blockIdx.y * 64;
    const float* W = (e == 0) ? wq : (e == 1) ? wk : wv;
    const int tid = threadIdx.x;

    for (int idx = tid; idx < 64 * 16; idx += 256) {
        const int i = idx >> 4, j4 = (idx & 15) << 2;
        *(float4*)&t[i][j4] = *(const float4*)(W + (size_t)(k0 + i) * 512 + n0 + j4);
    }
    __syncthreads();

    const int n_loc = tid >> 2;
    const int kq    = (tid & 3) << 4;
    unsigned short h[16], l[16];
    #pragma unroll
    for (int tt = 0; tt < 16; tt++) {
        const float x = t[kq + tt][n_loc];
        h[tt] = f2bf(x);
        l[tt] = f2bf(x - bf2f(h[tt]));
    }
    unsigned short* base = WpT + (size_t)e * 512 * K3 + (size_t)(n0 + n_loc) * K3 + k0 + kq;
    #pragma unroll
    for (int g4 = 0; g4 < 4; g4++) {
        ushort4 hv = make_ushort4(h[g4*4], h[g4*4+1], h[g4*4+2], h[g4*4+3]);
        ushort4 lv = make_ushort4(l[g4*4], l[g4*4+1], l[g4*4+2], l[g4*4+3]);
        *(ushort4*)(base + g4*4)        = hv;
        *(ushort4*)(base + 512 + g4*4)  = lv;
        *(ushort4*)(base + 1024 + g4*4) = hv;
    }
}

// ---------------------------------------------------------------------------
// Kernel 1: bf16-split MFMA GEMM. 128x128 tile, BK=32, 4 waves.
// e in {0,1} (Q,K): K'=1536 (hi,hi,lo x hi,lo,hi). e==2 (V): K'=512 (hi*hi).
// ---------------------------------------------------------------------------
__global__ __launch_bounds__(256)
void gemm_mfma(const unsigned short* __restrict__ Xp,
               const unsigned short* __restrict__ WpT,
               const float* __restrict__ bq, const float* __restrict__ bk,
               const float* __restrict__ bv,
               float* __restrict__ Qo, float* __restrict__ Ko,
               float* __restrict__ Vo)
{
    __shared__ __align__(16) unsigned short smA[4096];
    __shared__ __align__(16) unsigned short smB[4096];

    const int e = blockIdx.z;
    const float* bias = (e == 0) ? bq : (e == 1) ? bk : bv;
    float* C          = (e == 0) ? Qo : (e == 1) ? Ko : Vo;
    const unsigned short* Ag = Xp  + (size_t)e * 8192 * XPW;
    const unsigned short* Bg = WpT + (size_t)e * 512 * K3;
    const int kEnd = (e == 2) ? 512 : K3;

    const int tid  = threadIdx.x;
    const int lane = tid & 63;
    const int wid  = tid >> 6;
    const int wm   = wid & 1;
    const int wn   = wid >> 1;
    const int m0   = blockIdx.x * 128;
    const int n0g  = blockIdx.y * 128;

    const int r1 = tid >> 2;
    const int c8 = (((tid & 3) ^ ((r1 >> 1) & 3)) << 3);
    const unsigned short* agp = Ag + (size_t)(m0 + r1) * XPW + c8;
    const unsigned short* bgp = Bg + (size_t)(n0g + r1) * K3 + c8;
    unsigned short* lA1 = smA + (size_t)(tid & ~63) * 8;
    unsigned short* lA2 = lA1 + 2048;
    unsigned short* lB1 = smB + (size_t)(tid & ~63) * 8;
    unsigned short* lB2 = lB1 + 2048;

    const int r    = lane & 15;
    const int quad = lane >> 4;
    const int swz  = ((quad ^ ((lane >> 1) & 3)) << 4);
    const char* pA = (const char*)smA + (wm * 64 + r) * 64 + swz;
    const char* pB = (const char*)smB + (wn * 64 + r) * 64 + swz;

    f32x4 acc[4][4];
    #pragma unroll
    for (int i = 0; i < 4; i++)
        #pragma unroll
        for (int j = 0; j < 4; j++)
            acc[i][j] = (f32x4){0.f, 0.f, 0.f, 0.f};

    for (int k0 = 0; k0 < kEnd; k0 += 32) {
        const int kA = (k0 < 512) ? k0 : k0 - 512;
        lds_load16(agp + kA, lA1);
        lds_load16(agp + (size_t)64 * XPW + kA, lA2);
        lds_load16(bgp + k0, lB1);
        lds_load16(bgp + (size_t)64 * K3 + k0, lB2);
        __syncthreads();

        s16x8 af[4], bf[4];
        #pragma unroll
        for (int mt = 0; mt < 4; mt++) af[mt] = *(const s16x8*)(pA + mt * 1024);
        #pragma unroll
        for (int nt = 0; nt < 4; nt++) bf[nt] = *(const s16x8*)(pB + nt * 1024);
        #pragma unroll
        for (int mt = 0; mt < 4; mt++)
            #pragma unroll
            for (int nt = 0; nt < 4; nt++)
                acc[mt][nt] = __builtin_amdgcn_mfma_f32_16x16x32_bf16(
                    af[mt], bf[nt], acc[mt][nt], 0, 0, 0);
        __syncthreads();
    }

    #pragma unroll
    for (int nt = 0; nt < 4; nt++) {
        const int col = n0g + wn * 64 + nt * 16 + r;
        const float bb = bias[col];
        #pragma unroll
        for (int mt = 0; mt < 4; mt++) {
            const int row0 = m0 + wm * 64 + mt * 16 + quad * 4;
            #pragma unroll
            for (int i = 0; i < 4; i++)
                C[(size_t)(row0 + i) * 512 + col] = acc[mt][nt][i] + bb;
        }
    }
}

// ---------------------------------------------------------------------------
// Kernel 2: m[b,h,l] = max_s(q.k_s) - sum_s(q.k_s)/L. Wave per query.
// 4-lane cooperative row loads.
// ---------------------------------------------------------------------------
__global__ __launch_bounds__(256)
void sample_m(const float* __restrict__ Q, const float* __restrict__ K,
              const int* __restrict__ idx, float* __restrict__ m_out, int S)
{
    __shared__ float qs[4][DH];

    const int lane = threadIdx.x & 63;
    const int wib  = threadIdx.x >> 6;
    const int wid  = blockIdx.x * 4 + wib;
    const int l = wid & (L - 1);
    const int h = (wid >> 12) & (H - 1);
    const int b = wid >> 15;

    qs[wib][lane] = Q[((size_t)b * L + l) * D + h * DH + lane];
    __syncthreads();

    const int r4 = lane >> 2;
    const int c4 = lane & 3;

    float4 qf[4];
    {
        const float4* qv = (const float4*)qs[wib];
        #pragma unroll
        for (int i = 0; i < 4; i++) qf[i] = qv[c4 + 4 * i];
    }

    const float* Kb = K + (size_t)b * L * D + h * DH;
    const int* is = idx + (size_t)l * S;

    float vmax = -INFINITY, vsum = 0.f;
    const int passes = (S + 15) >> 4;
    for (int p = 0; p < passes; p++) {
        const int sp = p * 16 + r4;
        const bool ok = sp < S;
        const int j = ok ? is[sp] : 0;
        const float4* Krow = (const float4*)(Kb + (size_t)j * D);
        float dot = 0.f;
        #pragma unroll
        for (int i = 0; i < 4; i++) {
            const float4 kv = Krow[c4 + 4 * i];
            const float4 qq = qf[i];
            dot += qq.x * kv.x + qq.y * kv.y + qq.z * kv.z + qq.w * kv.w;
        }
        dot += __shfl_xor(dot, 1, 64);
        dot += __shfl_xor(dot, 2, 64);
        if (ok) {
            vmax = fmaxf(vmax, dot);
            if (c4 == 0) vsum += dot;
        }
    }
    #pragma unroll
    for (int off = 32; off; off >>= 1) {
        vmax = fmaxf(vmax, __shfl_xor(vmax, off, 64));
        vsum += __shfl_xor(vsum, off, 64);
    }
    if (lane == 0) m_out[wid] = vmax - vsum * (1.0f / (float)L);
}

// ---------------------------------------------------------------------------
// Kernel 3: exact top-NT via 4-level byte radix-select. One block per (b,h).
// Also zeroes sums[] for the attention stage.
// ---------------------------------------------------------------------------
__global__ __launch_bounds__(256)
void topk_kernel(const float* __restrict__ m_in, int* __restrict__ m_top,
                 float* __restrict__ sums, int NT)
{
    __shared__ unsigned hist[256];
    __shared__ unsigned sfx[257];
    __shared__ int sh_b, sh_rem;
    __shared__ int cnt_gt, cnt_eq;
    __shared__ int eqlist[128];

    const float* m = m_in + (size_t)blockIdx.x * L;
    const int tid = threadIdx.x;
    int* out = m_top + blockIdx.x * NT;

    if (tid < NT) sums[blockIdx.x * NT + tid] = 0.f;

    unsigned uv[16];
    #pragma unroll
    for (int k = 0; k < 16; k++) {
        const float f = m[tid + k * 256];
        const unsigned x = __float_as_uint(f);
        uv[k] = (x & 0x80000000u) ? ~x : (x | 0x80000000u);
    }

    unsigned prefix = 0;
    int rem = NT;

    for (int level = 0; level < 4; level++) {
        const int shift = 24 - level * 8;
        hist[tid] = 0;
        if (tid == 0) { cnt_gt = 0; cnt_eq = 0; }
        __syncthreads();
        #pragma unroll
        for (int k = 0; k < 16; k++) {
            const bool part = (level == 0) || ((uv[k] >> (shift + 8)) == prefix);
            if (part) atomicAdd(&hist[(uv[k] >> shift) & 255], 1u);
        }
        __syncthreads();
        if (tid < 64) {
            const unsigned s0 = hist[4*tid+0], s1 = hist[4*tid+1];
            const unsigned s2 = hist[4*tid+2], s3 = hist[4*tid+3];
            const unsigned loc = s0 + s1 + s2 + s3;
            unsigned suf = loc;
            #pragma unroll
            for (int off = 1; off < 64; off <<= 1) {
                const unsigned t = __shfl_down(suf, off, 64);
                if (tid + off < 64) suf += t;
            }
            const unsigned tail = suf - loc;
            sfx[4*tid+3] = tail + s3;
            sfx[4*tid+2] = tail + s3 + s2;
            sfx[4*tid+1] = tail + s3 + s2 + s1;
            sfx[4*tid+0] = suf;
            if (tid == 0) sfx[256] = 0;
        }
        __syncthreads();
        if (sfx[tid + 1] < (unsigned)rem && (unsigned)rem <= sfx[tid]) {
            sh_b   = tid;
            sh_rem = rem - (int)sfx[tid + 1];
        }
        __syncthreads();
        prefix = (prefix << 8) | (unsigned)sh_b;
        rem    = sh_rem;
        __syncthreads();
    }

    const unsigned T = prefix;
    const int n_gt = NT - rem;

    #pragma unroll
    for (int k = 0; k < 16; k++) {
        if (uv[k] > T) {
            const int pos = atomicAdd(&cnt_gt, 1);
            out[pos] = tid + k * 256;
        } else if (uv[k] == T) {
            const int pos = atomicAdd(&cnt_eq, 1);
            if (pos < 128) eqlist[pos] = tid + k * 256;
        }
    }
    __syncthreads();
    if (tid == 0) {
        int n = cnt_eq < 128 ? cnt_eq : 128;
        for (int r = 0; r < rem; r++) {
            int best = 0x7fffffff, bi = 0;
            for (int i = 0; i < n; i++)
                if (eqlist[i] < best) { best = eqlist[i]; bi = i; }
            out[n_gt + r] = best;
            eqlist[bi] = 0x7fffffff;
        }
    }
}

// ---------------------------------------------------------------------------
// Kernels 4+5: cumsum(V) along L per (b,h,d), chunked scan, chunk = 64.
// ---------------------------------------------------------------------------
#define CH 64
__global__ __launch_bounds__(64)
void chunk_sums(const float* __restrict__ V, float* __restrict__ partial)
{
    const int c = blockIdx.x & 63;
    const int h = (blockIdx.x >> 6) & (H - 1);
    const int b = blockIdx.x >> 9;
    const int d = threadIdx.x;
    const float* base = V + (size_t)b * L * D + h * DH + d;
    float s = 0.f;
    const int l0 = c * CH;
    for (int i = 0; i < CH; i++) s += base[(size_t)(l0 + i) * D];
    partial[((size_t)((b * H + h) * 64 + c)) * DH + d] = s;
}

__global__ __launch_bounds__(64)
void cumsum_write(const float* __restrict__ V, const float* __restrict__ partial,
                  float* __restrict__ out)
{
    const int c = blockIdx.x & 63;
    const int h = (blockIdx.x >> 6) & (H - 1);
    const int b = blockIdx.x >> 9;
    const int d = threadIdx.x;
    const float* base  = V   + (size_t)b * L * D + h * DH + d;
    float*       obase = out + (size_t)b * L * D + h * DH + d;
    const float* pb = partial + (size_t)((b * H + h) * 64) * DH + d;
    float acc = 0.f;
    for (int cc = 0; cc < c; cc++) acc += pb[cc * DH];
    const int l0 = c * CH;
    for (int i = 0; i < CH; i++) {
        acc += base[(size_t)(l0 + i) * D];
        obase[(size_t)(l0 + i) * D] = acc;
    }
}

// ---------------------------------------------------------------------------
// Kernel 6a: exp-scores + per-u sums. Grid (keyChunk=8, uGroup=3, bh=16).
// Scores are bounded (|s| <~ 1.5 after *0.125) -> exp without max is safe.
// Writes exp(s) for j<=p, 0 beyond (buffer fully initialized). Per-u sum via
// wave butterfly + atomicAdd (sums zeroed by topk). Chunk-0 blocks also zero
// the selected output rows (cumsum_write completed; attn_wv adds later).
// ---------------------------------------------------------------------------
__global__ __launch_bounds__(256)
void attn_scores(const float* __restrict__ Q, const float* __restrict__ K,
                 const int* __restrict__ m_top, float* __restrict__ scores,
                 float* __restrict__ sums, float* __restrict__ out, int NT)
{
    __shared__ float qsh[15][DH];
    __shared__ int   psh[15];

    const int bh = blockIdx.z;
    const int h  = bh & (H - 1);
    const int b  = bh >> 3;
    const int ug = blockIdx.y;
    const int j0 = blockIdx.x * 512;
    const int tid = threadIdx.x;

    for (int i = tid; i < 15 * DH; i += 256) {
        const int u = i >> 6, d = i & 63;
        const int p = m_top[bh * NT + ug * 15 + u];
        if (d == 0) psh[u] = p;
        qsh[u][d] = Q[((size_t)b * L + p) * D + h * DH + d];
    }
    __syncthreads();

    if (blockIdx.x == 0) {      // zero the selected output rows (this ug)
        for (int i = tid; i < 15 * DH; i += 256) {
            const int u = i >> 6, d = i & 63;
            out[((size_t)b * L + psh[u]) * D + h * DH + d] = 0.f;
        }
    }

    const float* Kb = K + (size_t)b * L * D + h * DH;
    const int ja = j0 + tid;
    const int jb = ja + 256;
    float4 k0[16], k1[16];
    {
        const float4* ra = (const float4*)(Kb + (size_t)ja * D);
        const float4* rb = (const float4*)(Kb + (size_t)jb * D);
        #pragma unroll
        for (int i = 0; i < 16; i++) { k0[i] = ra[i]; k1[i] = rb[i]; }
    }

    for (int u = 0; u < 15; u++) {
        const int p = psh[u];
        const float4* qv = (const float4*)qsh[u];
        float d0 = 0.f, d1 = 0.f;
        #pragma unroll
        for (int i = 0; i < 16; i++) {
            const float4 q4 = qv[i];
            d0 += q4.x * k0[i].x + q4.y * k0[i].y + q4.z * k0[i].z + q4.w * k0[i].w;
            d1 += q4.x * k1[i].x + q4.y * k1[i].y + q4.z * k1[i].z + q4.w * k1[i].w;
        }
        const float e0 = (ja <= p) ? __expf(d0 * 0.125f) : 0.f;
        const float e1 = (jb <= p) ? __expf(d1 * 0.125f) : 0.f;
        float* srow = scores + (size_t)(bh * NT + ug * 15 + u) * L;
        srow[ja] = e0;
        srow[jb] = e1;
        float t = e0 + e1;
        #pragma unroll
        for (int off = 32; off; off >>= 1) t += __shfl_xor(t, off, 64);
        if ((tid & 63) == 0) atomicAdd(&sums[bh * NT + ug * 15 + u], t);
    }
}

// ---------------------------------------------------------------------------
// Kernel 6c: weighted-V accumulate. Grid (keyChunk=64, bh=16) = 1024 blocks.
// V chunk (64 keys) in vreg[64] per thread (lane=d, coalesced; 4 waves share
// via L1). Weights normalized by 1/sum in LDS. Each wave handles u = w,w+4,..
// and atomicAdds its complete (u,d) contribution into the zeroed output row.
// ---------------------------------------------------------------------------
__global__ __launch_bounds__(256)
void attn_wv(const float* __restrict__ scores, const float* __restrict__ V,
             const int* __restrict__ m_top, const float* __restrict__ sums,
             float* __restrict__ out, int NT)
{
    __shared__ float ssh[45][64];
    __shared__ float sinv[45];
    __shared__ int   psh[45];

    const int bh = blockIdx.y;
    const int h  = bh & (H - 1);
    const int b  = bh >> 3;
    const int j0 = blockIdx.x * 64;
    const int tid = threadIdx.x;
    const int d   = tid & 63;
    const int w   = tid >> 6;

    if (tid < NT) {
        psh[tid]  = m_top[bh * NT + tid];
        sinv[tid] = 1.0f / sums[bh * NT + tid];
    }

    const float* Vb = V + (size_t)b * L * D + h * DH + d;
    float vreg[64];
    #pragma unroll
    for (int i = 0; i < 64; i++) vreg[i] = Vb[(size_t)(j0 + i) * D];

    __syncthreads();
    for (int i = tid; i < NT * 64; i += 256) {
        const int u = i >> 6, j = i & 63;
        ssh[u][j] = scores[(size_t)(bh * NT + u) * L + j0 + j] * sinv[u];
    }
    __syncthreads();

    for (int u = w; u < NT; u += 4) {
        const int p = psh[u];
        if (p < j0) continue;               // wave-uniform branch
        const float* wt = ssh[u];
        float acc = 0.f;
        #pragma unroll
        for (int i = 0; i < 64; i++) acc += wt[i] * vreg[i];
        atomicAdd(out + ((size_t)b * L + p) * D + h * DH + d, acc);
    }
}

// ---------------------------------------------------------------------------
extern "C" void kernel_launch(void* const* d_in, const int* in_sizes, int n_in,
                              void* d_out, int out_size, void* d_ws, size_t ws_size,
                              hipStream_t stream)
{
    const float* queries = (const float*)d_in[0];
    const float* keys    = (const float*)d_in[1];
    const float* values  = (const float*)d_in[2];
    const float* Wq      = (const float*)d_in[3];
    const float* bq      = (const float*)d_in[4];
    const float* Wk      = (const float*)d_in[5];
    const float* bk      = (const float*)d_in[6];
    const float* Wv      = (const float*)d_in[7];
    const float* bv      = (const float*)d_in[8];
    const int*   idx     = (const int*)d_in[9];
    float* out = (float*)d_out;

    const int S  = in_sizes[9] / L;   // sample_k = 45
    const int NT = S;

    const size_t NE = (size_t)B * L * D;
    float* Qb      = (float*)d_ws;
    float* Kb      = Qb + NE;
    float* Vb      = Kb + NE;
    float* m_buf   = Vb + NE;                           // BH*L
    float* cs_part = m_buf + (size_t)BH * L;            // BH*64*DH
    int*   m_top   = (int*)(cs_part + (size_t)BH * 64 * DH);
    float* scores  = (float*)(m_top + 1024);            // BH*NT*L
    float* sums    = scores + (size_t)BH * NT * L;      // BH*NT
    unsigned short* Xp  = (unsigned short*)(sums + 1024);
    unsigned short* WpT = Xp + (size_t)3 * 8192 * XPW;  // 3*512*K3

    split_x<<<3 * 8192 * 128 / 256, 256, 0, stream>>>(queries, keys, values, Xp);
    split_w<<<dim3(8, 8, 3), 256, 0, stream>>>(Wq, Wk, Wv, WpT);

    gemm_mfma<<<dim3(8192 / 128, 512 / 128, 3), 256, 0, stream>>>(
        Xp, WpT, bq, bk, bv, Qb, Kb, Vb);

    sample_m<<<BH * L / 4, 256, 0, stream>>>(Qb, Kb, idx, m_buf, S);

    topk_kernel<<<BH, 256, 0, stream>>>(m_buf, m_top, sums, NT);

    chunk_sums<<<BH * 64, 64, 0, stream>>>(Vb, cs_part);
    cumsum_write<<<BH * 64, 64, 0, stream>>>(Vb, cs_part, out);

    attn_scores<<<dim3(8, 3, BH), 256, 0, stream>>>(Qb, Kb, m_top, scores, sums, out, NT);
    attn_wv<<<dim3(64, BH), 256, 0, stream>>>(scores, Vb, m_top, sums, out, NT);
}

// Round 9
// 277.191 us; speedup vs baseline: 4.6657x; 1.0059x over previous
//
#include <hip/hip_runtime.h>
#include <math.h>

#define B  2
#define L  4096
#define D  512
#define H  8
#define DH 64
#define BH (B * H)
#define K3 1536          // tripled-K for the bf16 split GEMM (Q,K)
#define XPW 1024         // Xp width: [hi | lo]

typedef short s16x8 __attribute__((ext_vector_type(8)));
typedef float f32x4 __attribute__((ext_vector_type(4)));

#define AS1 __attribute__((address_space(1)))
#define AS3 __attribute__((address_space(3)))

__device__ __forceinline__ void lds_load16(const void* g, void* l) {
    __builtin_amdgcn_global_load_lds((const AS1 unsigned int*)g,
                                     (AS3 unsigned int*)l, 16, 0, 0);
}

__device__ __forceinline__ unsigned short f2bf(float x) {
    union { float f; unsigned u; } v; v.f = x;
    unsigned u = v.u;
    return (unsigned short)((u + 0x7fff + ((u >> 16) & 1)) >> 16);
}
__device__ __forceinline__ float bf2f(unsigned short h) {
    union { float f; unsigned u; } v; v.u = ((unsigned)h) << 16;
    return v.f;
}

// ---------------------------------------------------------------------------
// Prep 1: split X (fp32 8192x512) -> Xp (bf16 8192x1024): [hi | lo]
// V (e==2) needs only hi (bf16 GEMM): skip lo store.
// ---------------------------------------------------------------------------
__global__ __launch_bounds__(256)
void split_x(const float* __restrict__ q, const float* __restrict__ k,
             const float* __restrict__ v, unsigned short* __restrict__ Xp)
{
    const size_t g = (size_t)blockIdx.x * 256 + threadIdx.x;
    const size_t per = (size_t)8192 * 128;
    const int e = (int)(g / per);
    const size_t rem = g - (size_t)e * per;
    const int m  = (int)(rem >> 7);
    const int kq = (int)(rem & 127) << 2;

    const float* X = (e == 0) ? q : (e == 1) ? k : v;
    const float4 x = *(const float4*)(X + (size_t)m * 512 + kq);

    unsigned short h0 = f2bf(x.x), h1 = f2bf(x.y), h2 = f2bf(x.z), h3 = f2bf(x.w);

    unsigned short* dst = Xp + (size_t)e * 8192 * XPW + (size_t)m * XPW + kq;
    *(ushort4*)(dst) = make_ushort4(h0, h1, h2, h3);
    if (e != 2) {
        unsigned short l0 = f2bf(x.x - bf2f(h0)), l1 = f2bf(x.y - bf2f(h1));
        unsigned short l2 = f2bf(x.z - bf2f(h2)), l3 = f2bf(x.w - bf2f(h3));
        *(ushort4*)(dst + 512) = make_ushort4(l0, l1, l2, l3);
    }
}

// ---------------------------------------------------------------------------
// Prep 2: W (fp32 512x512, [k][n]) -> WpT (bf16 512x1536, [n][k']):
//   k' in [0,512): hi   [512,1024): lo   [1024,1536): hi
// ---------------------------------------------------------------------------
__global__ __launch_bounds__(256)
void split_w(const float* __restrict__ wq, const float* __restrict__ wk,
             const float* __restrict__ wv, unsigned short* __restrict__ WpT)
{
    __shared__ float t[64][65];
    const int e  = blockIdx.z;
    const int k0 = blockIdx.x * 64;
    const int n0 = blockIdx.y * 64;
    const float* W = (e == 0) ? wq : (e == 1) ? wk : wv;
    const int tid = threadIdx.x;

    for (int idx = tid; idx < 64 * 16; idx += 256) {
        const int i = idx >> 4, j4 = (idx & 15) << 2;
        *(float4*)&t[i][j4] = *(const float4*)(W + (size_t)(k0 + i) * 512 + n0 + j4);
    }
    __syncthreads();

    const int n_loc = tid >> 2;
    const int kq    = (tid & 3) << 4;
    unsigned short h[16], l[16];
    #pragma unroll
    for (int tt = 0; tt < 16; tt++) {
        const float x = t[kq + tt][n_loc];
        h[tt] = f2bf(x);
        l[tt] = f2bf(x - bf2f(h[tt]));
    }
    unsigned short* base = WpT + (size_t)e * 512 * K3 + (size_t)(n0 + n_loc) * K3 + k0 + kq;
    #pragma unroll
    for (int g4 = 0; g4 < 4; g4++) {
        ushort4 hv = make_ushort4(h[g4*4], h[g4*4+1], h[g4*4+2], h[g4*4+3]);
        ushort4 lv = make_ushort4(l[g4*4], l[g4*4+1], l[g4*4+2], l[g4*4+3]);
        *(ushort4*)(base + g4*4)        = hv;
        *(ushort4*)(base + 512 + g4*4)  = lv;
        *(ushort4*)(base + 1024 + g4*4) = hv;
    }
}

// ---------------------------------------------------------------------------
// Kernel 1: bf16-split MFMA GEMM. 128x128 tile, BK=32, 4 waves.
// e in {0,1} (Q,K): K'=1536. e==2 (V): K'=512 (hi*hi).
// ---------------------------------------------------------------------------
__global__ __launch_bounds__(256)
void gemm_mfma(const unsigned short* __restrict__ Xp,
               const unsigned short* __restrict__ WpT,
               const float* __restrict__ bq, const float* __restrict__ bk,
               const float* __restrict__ bv,
               float* __restrict__ Qo, float* __restrict__ Ko,
               float* __restrict__ Vo)
{
    __shared__ __align__(16) unsigned short smA[4096];
    __shared__ __align__(16) unsigned short smB[4096];

    const int e = blockIdx.z;
    const float* bias = (e == 0) ? bq : (e == 1) ? bk : bv;
    float* C          = (e == 0) ? Qo : (e == 1) ? Ko : Vo;
    const unsigned short* Ag = Xp  + (size_t)e * 8192 * XPW;
    const unsigned short* Bg = WpT + (size_t)e * 512 * K3;
    const int kEnd = (e == 2) ? 512 : K3;

    const int tid  = threadIdx.x;
    const int lane = tid & 63;
    const int wid  = tid >> 6;
    const int wm   = wid & 1;
    const int wn   = wid >> 1;
    const int m0   = blockIdx.x * 128;
    const int n0g  = blockIdx.y * 128;

    const int r1 = tid >> 2;
    const int c8 = (((tid & 3) ^ ((r1 >> 1) & 3)) << 3);
    const unsigned short* agp = Ag + (size_t)(m0 + r1) * XPW + c8;
    const unsigned short* bgp = Bg + (size_t)(n0g + r1) * K3 + c8;
    unsigned short* lA1 = smA + (size_t)(tid & ~63) * 8;
    unsigned short* lA2 = lA1 + 2048;
    unsigned short* lB1 = smB + (size_t)(tid & ~63) * 8;
    unsigned short* lB2 = lB1 + 2048;

    const int r    = lane & 15;
    const int quad = lane >> 4;
    const int swz  = ((quad ^ ((lane >> 1) & 3)) << 4);
    const char* pA = (const char*)smA + (wm * 64 + r) * 64 + swz;
    const char* pB = (const char*)smB + (wn * 64 + r) * 64 + swz;

    f32x4 acc[4][4];
    #pragma unroll
    for (int i = 0; i < 4; i++)
        #pragma unroll
        for (int j = 0; j < 4; j++)
            acc[i][j] = (f32x4){0.f, 0.f, 0.f, 0.f};

    for (int k0 = 0; k0 < kEnd; k0 += 32) {
        const int kA = (k0 < 512) ? k0 : k0 - 512;
        lds_load16(agp + kA, lA1);
        lds_load16(agp + (size_t)64 * XPW + kA, lA2);
        lds_load16(bgp + k0, lB1);
        lds_load16(bgp + (size_t)64 * K3 + k0, lB2);
        __syncthreads();

        s16x8 af[4], bf[4];
        #pragma unroll
        for (int mt = 0; mt < 4; mt++) af[mt] = *(const s16x8*)(pA + mt * 1024);
        #pragma unroll
        for (int nt = 0; nt < 4; nt++) bf[nt] = *(const s16x8*)(pB + nt * 1024);
        #pragma unroll
        for (int mt = 0; mt < 4; mt++)
            #pragma unroll
            for (int nt = 0; nt < 4; nt++)
                acc[mt][nt] = __builtin_amdgcn_mfma_f32_16x16x32_bf16(
                    af[mt], bf[nt], acc[mt][nt], 0, 0, 0);
        __syncthreads();
    }

    #pragma unroll
    for (int nt = 0; nt < 4; nt++) {
        const int col = n0g + wn * 64 + nt * 16 + r;
        const float bb = bias[col];
        #pragma unroll
        for (int mt = 0; mt < 4; mt++) {
            const int row0 = m0 + wm * 64 + mt * 16 + quad * 4;
            #pragma unroll
            for (int i = 0; i < 4; i++)
                C[(size_t)(row0 + i) * 512 + col] = acc[mt][nt][i] + bb;
        }
    }
}

// ---------------------------------------------------------------------------
// Kernel 2: m[b,h,l] = max_s(q.k_s) - sum_s(q.k_s)/L. Wave per query.
// 4-lane cooperative row loads.
// ---------------------------------------------------------------------------
__global__ __launch_bounds__(256)
void sample_m(const float* __restrict__ Q, const float* __restrict__ K,
              const int* __restrict__ idx, float* __restrict__ m_out, int S)
{
    __shared__ float qs[4][DH];

    const int lane = threadIdx.x & 63;
    const int wib  = threadIdx.x >> 6;
    const int wid  = blockIdx.x * 4 + wib;
    const int l = wid & (L - 1);
    const int h = (wid >> 12) & (H - 1);
    const int b = wid >> 15;

    qs[wib][lane] = Q[((size_t)b * L + l) * D + h * DH + lane];
    __syncthreads();

    const int r4 = lane >> 2;
    const int c4 = lane & 3;

    float4 qf[4];
    {
        const float4* qv = (const float4*)qs[wib];
        #pragma unroll
        for (int i = 0; i < 4; i++) qf[i] = qv[c4 + 4 * i];
    }

    const float* Kb = K + (size_t)b * L * D + h * DH;
    const int* is = idx + (size_t)l * S;

    float vmax = -INFINITY, vsum = 0.f;
    const int passes = (S + 15) >> 4;
    for (int p = 0; p < passes; p++) {
        const int sp = p * 16 + r4;
        const bool ok = sp < S;
        const int j = ok ? is[sp] : 0;
        const float4* Krow = (const float4*)(Kb + (size_t)j * D);
        float dot = 0.f;
        #pragma unroll
        for (int i = 0; i < 4; i++) {
            const float4 kv = Krow[c4 + 4 * i];
            const float4 qq = qf[i];
            dot += qq.x * kv.x + qq.y * kv.y + qq.z * kv.z + qq.w * kv.w;
        }
        dot += __shfl_xor(dot, 1, 64);
        dot += __shfl_xor(dot, 2, 64);
        if (ok) {
            vmax = fmaxf(vmax, dot);
            if (c4 == 0) vsum += dot;
        }
    }
    #pragma unroll
    for (int off = 32; off; off >>= 1) {
        vmax = fmaxf(vmax, __shfl_xor(vmax, off, 64));
        vsum += __shfl_xor(vsum, off, 64);
    }
    if (lane == 0) m_out[wid] = vmax - vsum * (1.0f / (float)L);
}

// ---------------------------------------------------------------------------
// Kernel 3: exact top-NT via 4-level byte radix-select. One block per (b,h).
// Also zeroes sums[] for the attention stage.
// ---------------------------------------------------------------------------
__global__ __launch_bounds__(256)
void topk_kernel(const float* __restrict__ m_in, int* __restrict__ m_top,
                 float* __restrict__ sums, int NT)
{
    __shared__ unsigned hist[256];
    __shared__ unsigned sfx[257];
    __shared__ int sh_b, sh_rem;
    __shared__ int cnt_gt, cnt_eq;
    __shared__ int eqlist[128];

    const float* m = m_in + (size_t)blockIdx.x * L;
    const int tid = threadIdx.x;
    int* out = m_top + blockIdx.x * NT;

    if (tid < NT) sums[blockIdx.x * NT + tid] = 0.f;

    unsigned uv[16];
    #pragma unroll
    for (int k = 0; k < 16; k++) {
        const float f = m[tid + k * 256];
        const unsigned x = __float_as_uint(f);
        uv[k] = (x & 0x80000000u) ? ~x : (x | 0x80000000u);
    }

    unsigned prefix = 0;
    int rem = NT;

    for (int level = 0; level < 4; level++) {
        const int shift = 24 - level * 8;
        hist[tid] = 0;
        if (tid == 0) { cnt_gt = 0; cnt_eq = 0; }
        __syncthreads();
        #pragma unroll
        for (int k = 0; k < 16; k++) {
            const bool part = (level == 0) || ((uv[k] >> (shift + 8)) == prefix);
            if (part) atomicAdd(&hist[(uv[k] >> shift) & 255], 1u);
        }
        __syncthreads();
        if (tid < 64) {
            const unsigned s0 = hist[4*tid+0], s1 = hist[4*tid+1];
            const unsigned s2 = hist[4*tid+2], s3 = hist[4*tid+3];
            const unsigned loc = s0 + s1 + s2 + s3;
            unsigned suf = loc;
            #pragma unroll
            for (int off = 1; off < 64; off <<= 1) {
                const unsigned t = __shfl_down(suf, off, 64);
                if (tid + off < 64) suf += t;
            }
            const unsigned tail = suf - loc;
            sfx[4*tid+3] = tail + s3;
            sfx[4*tid+2] = tail + s3 + s2;
            sfx[4*tid+1] = tail + s3 + s2 + s1;
            sfx[4*tid+0] = suf;
            if (tid == 0) sfx[256] = 0;
        }
        __syncthreads();
        if (sfx[tid + 1] < (unsigned)rem && (unsigned)rem <= sfx[tid]) {
            sh_b   = tid;
            sh_rem = rem - (int)sfx[tid + 1];
        }
        __syncthreads();
        prefix = (prefix << 8) | (unsigned)sh_b;
        rem    = sh_rem;
        __syncthreads();
    }

    const unsigned T = prefix;
    const int n_gt = NT - rem;

    #pragma unroll
    for (int k = 0; k < 16; k++) {
        if (uv[k] > T) {
            const int pos = atomicAdd(&cnt_gt, 1);
            out[pos] = tid + k * 256;
        } else if (uv[k] == T) {
            const int pos = atomicAdd(&cnt_eq, 1);
            if (pos < 128) eqlist[pos] = tid + k * 256;
        }
    }
    __syncthreads();
    if (tid == 0) {
        int n = cnt_eq < 128 ? cnt_eq : 128;
        for (int r = 0; r < rem; r++) {
            int best = 0x7fffffff, bi = 0;
            for (int i = 0; i < n; i++)
                if (eqlist[i] < best) { best = eqlist[i]; bi = i; }
            out[n_gt + r] = best;
            eqlist[bi] = 0x7fffffff;
        }
    }
}

// ---------------------------------------------------------------------------
// Kernels 4+5: cumsum(V) along L per (b,h,d), chunked scan, chunk = 64.
// v2: 256-thread blocks, wave-per-chunk; all 64 loads issued into registers
// BEFORE the serial scan (one latency round-trip instead of 64).
// ---------------------------------------------------------------------------
#define CH 64
__global__ __launch_bounds__(256)
void chunk_sums(const float* __restrict__ V, float* __restrict__ partial)
{
    const int c  = (blockIdx.x & 15) * 4 + (threadIdx.x >> 6);
    const int h  = (blockIdx.x >> 4) & (H - 1);
    const int b  = blockIdx.x >> 7;
    const int d  = threadIdx.x & 63;
    const float* base = V + (size_t)b * L * D + h * DH + d + (size_t)(c * CH) * D;

    float vals[CH];
    #pragma unroll
    for (int i = 0; i < CH; i++) vals[i] = base[(size_t)i * D];

    float s0 = 0.f, s1 = 0.f, s2 = 0.f, s3 = 0.f;
    #pragma unroll
    for (int i = 0; i < CH; i += 4) {
        s0 += vals[i]; s1 += vals[i+1]; s2 += vals[i+2]; s3 += vals[i+3];
    }
    partial[((size_t)((b * H + h) * 64 + c)) * DH + d] = (s0 + s1) + (s2 + s3);
}

__global__ __launch_bounds__(256)
void cumsum_write(const float* __restrict__ V, const float* __restrict__ partial,
                  float* __restrict__ out)
{
    const int c  = (blockIdx.x & 15) * 4 + (threadIdx.x >> 6);
    const int h  = (blockIdx.x >> 4) & (H - 1);
    const int b  = blockIdx.x >> 7;
    const int d  = threadIdx.x & 63;
    const size_t off = (size_t)b * L * D + h * DH + d + (size_t)(c * CH) * D;
    const float* base  = V   + off;
    float*       obase = out + off;
    const float* pb = partial + (size_t)((b * H + h) * 64) * DH + d;

    float vals[CH];
    #pragma unroll
    for (int i = 0; i < CH; i++) vals[i] = base[(size_t)i * D];

    float acc = 0.f;
    for (int cc = 0; cc < c; cc++) acc += pb[cc * DH];   // wave-uniform trip

    #pragma unroll
    for (int i = 0; i < CH; i++) {
        acc += vals[i];
        obase[(size_t)i * D] = acc;
    }
}

// ---------------------------------------------------------------------------
// Kernel 6a: exp-scores + per-u sums. Grid (keyChunk=8, uGroup=3, bh=16).
// Chunk-0 blocks also zero the selected output rows.
// ---------------------------------------------------------------------------
__global__ __launch_bounds__(256)
void attn_scores(const float* __restrict__ Q, const float* __restrict__ K,
                 const int* __restrict__ m_top, float* __restrict__ scores,
                 float* __restrict__ sums, float* __restrict__ out, int NT)
{
    __shared__ float qsh[15][DH];
    __shared__ int   psh[15];

    const int bh = blockIdx.z;
    const int h  = bh & (H - 1);
    const int b  = bh >> 3;
    const int ug = blockIdx.y;
    const int j0 = blockIdx.x * 512;
    const int tid = threadIdx.x;

    for (int i = tid; i < 15 * DH; i += 256) {
        const int u = i >> 6, d = i & 63;
        const int p = m_top[bh * NT + ug * 15 + u];
        if (d == 0) psh[u] = p;
        qsh[u][d] = Q[((size_t)b * L + p) * D + h * DH + d];
    }
    __syncthreads();

    if (blockIdx.x == 0) {
        for (int i = tid; i < 15 * DH; i += 256) {
            const int u = i >> 6, d = i & 63;
            out[((size_t)b * L + psh[u]) * D + h * DH + d] = 0.f;
        }
    }

    const float* Kb = K + (size_t)b * L * D + h * DH;
    const int ja = j0 + tid;
    const int jb = ja + 256;
    float4 k0[16], k1[16];
    {
        const float4* ra = (const float4*)(Kb + (size_t)ja * D);
        const float4* rb = (const float4*)(Kb + (size_t)jb * D);
        #pragma unroll
        for (int i = 0; i < 16; i++) { k0[i] = ra[i]; k1[i] = rb[i]; }
    }

    for (int u = 0; u < 15; u++) {
        const int p = psh[u];
        const float4* qv = (const float4*)qsh[u];
        float d0 = 0.f, d1 = 0.f;
        #pragma unroll
        for (int i = 0; i < 16; i++) {
            const float4 q4 = qv[i];
            d0 += q4.x * k0[i].x + q4.y * k0[i].y + q4.z * k0[i].z + q4.w * k0[i].w;
            d1 += q4.x * k1[i].x + q4.y * k1[i].y + q4.z * k1[i].z + q4.w * k1[i].w;
        }
        const float e0 = (ja <= p) ? __expf(d0 * 0.125f) : 0.f;
        const float e1 = (jb <= p) ? __expf(d1 * 0.125f) : 0.f;
        float* srow = scores + (size_t)(bh * NT + ug * 15 + u) * L;
        srow[ja] = e0;
        srow[jb] = e1;
        float t = e0 + e1;
        #pragma unroll
        for (int off = 32; off; off >>= 1) t += __shfl_xor(t, off, 64);
        if ((tid & 63) == 0) atomicAdd(&sums[bh * NT + ug * 15 + u], t);
    }
}

// ---------------------------------------------------------------------------
// Kernel 6c: weighted-V accumulate into zeroed output rows via atomics.
// ---------------------------------------------------------------------------
__global__ __launch_bounds__(256)
void attn_wv(const float* __restrict__ scores, const float* __restrict__ V,
             const int* __restrict__ m_top, const float* __restrict__ sums,
             float* __restrict__ out, int NT)
{
    __shared__ float ssh[45][64];
    __shared__ float sinv[45];
    __shared__ int   psh[45];

    const int bh = blockIdx.y;
    const int h  = bh & (H - 1);
    const int b  = bh >> 3;
    const int j0 = blockIdx.x * 64;
    const int tid = threadIdx.x;
    const int d   = tid & 63;
    const int w   = tid >> 6;

    if (tid < NT) {
        psh[tid]  = m_top[bh * NT + tid];
        sinv[tid] = 1.0f / sums[bh * NT + tid];
    }

    const float* Vb = V + (size_t)b * L * D + h * DH + d;
    float vreg[64];
    #pragma unroll
    for (int i = 0; i < 64; i++) vreg[i] = Vb[(size_t)(j0 + i) * D];

    __syncthreads();
    for (int i = tid; i < NT * 64; i += 256) {
        const int u = i >> 6, j = i & 63;
        ssh[u][j] = scores[(size_t)(bh * NT + u) * L + j0 + j] * sinv[u];
    }
    __syncthreads();

    for (int u = w; u < NT; u += 4) {
        const int p = psh[u];
        if (p < j0) continue;
        const float* wt = ssh[u];
        float acc = 0.f;
        #pragma unroll
        for (int i = 0; i < 64; i++) acc += wt[i] * vreg[i];
        atomicAdd(out + ((size_t)b * L + p) * D + h * DH + d, acc);
    }
}

// ---------------------------------------------------------------------------
extern "C" void kernel_launch(void* const* d_in, const int* in_sizes, int n_in,
                              void* d_out, int out_size, void* d_ws, size_t ws_size,
                              hipStream_t stream)
{
    const float* queries = (const float*)d_in[0];
    const float* keys    = (const float*)d_in[1];
    const float* values  = (const float*)d_in[2];
    const float* Wq      = (const float*)d_in[3];
    const float* bq      = (const float*)d_in[4];
    const float* Wk      = (const float*)d_in[5];
    const float* bk      = (const float*)d_in[6];
    const float* Wv      = (const float*)d_in[7];
    const float* bv      = (const float*)d_in[8];
    const int*   idx     = (const int*)d_in[9];
    float* out = (float*)d_out;

    const int S  = in_sizes[9] / L;   // sample_k = 45
    const int NT = S;

    const size_t NE = (size_t)B * L * D;
    float* Qb      = (float*)d_ws;
    float* Kb      = Qb + NE;
    float* Vb      = Kb + NE;
    float* m_buf   = Vb + NE;                           // BH*L
    float* cs_part = m_buf + (size_t)BH * L;            // BH*64*DH
    int*   m_top   = (int*)(cs_part + (size_t)BH * 64 * DH);
    float* scores  = (float*)(m_top + 1024);            // BH*NT*L
    float* sums    = scores + (size_t)BH * NT * L;      // BH*NT
    unsigned short* Xp  = (unsigned short*)(sums + 1024);
    unsigned short* WpT = Xp + (size_t)3 * 8192 * XPW;  // 3*512*K3

    split_x<<<3 * 8192 * 128 / 256, 256, 0, stream>>>(queries, keys, values, Xp);
    split_w<<<dim3(8, 8, 3), 256, 0, stream>>>(Wq, Wk, Wv, WpT);

    gemm_mfma<<<dim3(8192 / 128, 512 / 128, 3), 256, 0, stream>>>(
        Xp, WpT, bq, bk, bv, Qb, Kb, Vb);

    sample_m<<<BH * L / 4, 256, 0, stream>>>(Qb, Kb, idx, m_buf, S);

    topk_kernel<<<BH, 256, 0, stream>>>(m_buf, m_top, sums, NT);

    chunk_sums<<<BH * 16, 256, 0, stream>>>(Vb, cs_part);
    cumsum_write<<<BH * 16, 256, 0, stream>>>(Vb, cs_part, out);

    attn_scores<<<dim3(8, 3, BH), 256, 0, stream>>>(Qb, Kb, m_top, scores, sums, out, NT);
    attn_wv<<<dim3(64, BH), 256, 0, stream>>>(scores, Vb, m_top, sums, out, NT);
}